// Round 5
// baseline (285.328 us; speedup 1.0000x reference)
//
#include <hip/hip_runtime.h>
#include <hip/hip_fp16.h>

#define N_NODES 50000
#define N_EDGES 800000
#define NBINS   391          // ceil(50000/128), 128 dst nodes per bin
#define EPB     4096         // edges per block (bhist / binA)
#define NBLK_E  ((N_EDGES + EPB - 1) / EPB)
#define MAXSEG  4096         // pass-B LDS segment capacity (mean 2046)
#define NPW     16           // nodes per wave in pre-GEMM kernels
#define NWAVES_PRE (N_NODES / NPW)   // 3125

// ---------------- bin-level histogram ----------------
__global__ void k_bhist(const int* __restrict__ dst, int* __restrict__ bincnt) {
    __shared__ int cnt[NBINS];
    int t = threadIdx.x;
    for (int i = t; i < NBINS; i += 256) cnt[i] = 0;
    __syncthreads();
    int base = blockIdx.x * EPB;
    int nE = min(EPB, N_EDGES - base);
    for (int i = t; i < nE; i += 256) atomicAdd(&cnt[dst[base + i] >> 7], 1);
    __syncthreads();
    for (int i = t; i < NBINS; i += 256) if (cnt[i]) atomicAdd(&bincnt[i], cnt[i]);
}

// ---------------- exclusive scan of bin counts ----------------
__global__ void k_bscan(const int* __restrict__ bincnt, int* __restrict__ binoff,
                        int* __restrict__ bincur) {
    __shared__ int tmp[512];
    int t = threadIdx.x;
    int v = (t < NBINS) ? bincnt[t] : 0;
    tmp[t] = v;
    __syncthreads();
    int val = v;
    for (int d = 1; d < 512; d <<= 1) {
        int add = (t >= d) ? tmp[t - d] : 0;
        __syncthreads();
        val += add;
        tmp[t] = val;
        __syncthreads();
    }
    if (t < NBINS) { binoff[t] = val - v; bincur[t] = val - v; }
    if (t == NBINS - 1) binoff[NBINS] = val;
}

// ---------------- pass A: LDS-staged bin scatter ----------------
__global__ void k_binA(const int* __restrict__ src, const int* __restrict__ dst,
                       int* __restrict__ bincur, int* __restrict__ binned) {
    __shared__ int cnt[NBINS];
    __shared__ int sscan[NBINS];
    __shared__ int lpos[NBINS];
    __shared__ int base[NBINS];
    __shared__ int stage[EPB];
    __shared__ unsigned short sbin[EPB];
    int t = threadIdx.x;
    int blkbase = blockIdx.x * EPB;
    int nE = min(EPB, N_EDGES - blkbase);
    for (int i = t; i < NBINS; i += 256) cnt[i] = 0;
    __syncthreads();
    int sv[16], dv[16];
#pragma unroll
    for (int k = 0; k < 16; ++k) {
        int e = blkbase + t + k * 256;
        if (e < N_EDGES) {
            sv[k] = src[e];
            dv[k] = dst[e];
            atomicAdd(&cnt[dv[k] >> 7], 1);
        } else dv[k] = -1;
    }
    __syncthreads();
    if (t == 0) {
        int run = 0;
        for (int b = 0; b < NBINS; ++b) { sscan[b] = run; run += cnt[b]; }
    }
    __syncthreads();
    for (int b = t; b < NBINS; b += 256) {
        lpos[b] = sscan[b];
        if (cnt[b] > 0) base[b] = atomicAdd(&bincur[b], cnt[b]);
    }
    __syncthreads();
#pragma unroll
    for (int k = 0; k < 16; ++k) {
        if (dv[k] >= 0) {
            int b = dv[k] >> 7;
            int p = atomicAdd(&lpos[b], 1);
            stage[p] = (sv[k] & 0xFFFF) | ((dv[k] & 127) << 16);
            sbin[p] = (unsigned short)b;
        }
    }
    __syncthreads();
    for (int i = t; i < nE; i += 256) {
        int b = sbin[i];
        binned[base[b] + (i - sscan[b])] = stage[i];
    }
}

// ---------------- pass B: per-bin counting sort; derives off[] ----------------
__global__ void k_binB(const int* __restrict__ binoff, const int* __restrict__ binned,
                       int* __restrict__ off, int* __restrict__ esrc) {
    __shared__ int cnt[128];
    __shared__ int tmp[128];
    __shared__ int cur[128];
    __shared__ int buf[MAXSEG];
    int b = blockIdx.x, t = threadIdx.x;
    int n0 = b << 7;
    int seg0 = binoff[b], seg1 = binoff[b + 1];
    int n = seg1 - seg0;
    if (t < 128) cnt[t] = 0;
    __syncthreads();
    for (int i = t; i < n; i += 256) atomicAdd(&cnt[binned[seg0 + i] >> 16], 1);
    __syncthreads();
    int v = (t < 128) ? cnt[t] : 0;
    if (t < 128) tmp[t] = v;
    __syncthreads();
    int val = v;
    for (int d = 1; d < 128; d <<= 1) {
        int add = (t >= d && t < 128) ? tmp[t - d] : 0;
        __syncthreads();
        if (t < 128) { val += add; tmp[t] = val; }
        __syncthreads();
    }
    if (t < 128) {
        int excl = val - v;
        cur[t] = excl;
        int node = n0 + t;
        if (node < N_NODES) off[node] = seg0 + excl;
    }
    __syncthreads();
    if (n <= MAXSEG) {
        for (int i = t; i < n; i += 256) {
            int w = binned[seg0 + i];
            int p = atomicAdd(&cur[w >> 16], 1);
            buf[p] = w & 0xFFFF;
        }
        __syncthreads();
        for (int i = t; i < n; i += 256) esrc[seg0 + i] = buf[i];
    } else {
        for (int i = t; i < n; i += 256) {
            int w = binned[seg0 + i];
            int p = atomicAdd(&cur[w >> 16], 1);
            esrc[seg0 + p] = w & 0xFFFF;
        }
    }
}

// ---------------- pre1: p = x@w1l (fp16), q = x@w1r + b1 (fp32) ----------------
// register-resident weight columns + shuffle row-broadcast; no LDS.
__global__ __launch_bounds__(256) void k_pre1(const float* __restrict__ x,
                                              const float* __restrict__ wl,
                                              const float* __restrict__ wr,
                                              const float* __restrict__ b,
                                              __half* __restrict__ ph,
                                              float* __restrict__ q) {
    int wv = threadIdx.x >> 6, lane = threadIdx.x & 63;
    int gw = blockIdx.x * 4 + wv;
    if (gw >= NWAVES_PRE) return;
    float wlc[64], wrc[64];
#pragma unroll
    for (int k = 0; k < 64; ++k) { wlc[k] = wl[k * 64 + lane]; wrc[k] = wr[k * 64 + lane]; }
    float bv = b[lane];
    int n0 = gw * NPW;
    for (int nn = 0; nn < NPW; ++nn) {
        int node = n0 + nn;
        float v = x[(size_t)node * 64 + lane];
        float pa = 0.f, qa = bv;
#pragma unroll
        for (int k = 0; k < 64; ++k) {
            float xk = __shfl(v, k);
            pa = fmaf(xk, wlc[k], pa);
            qa = fmaf(xk, wrc[k], qa);
        }
        q[(size_t)node * 64 + lane] = qa;
        float po = __shfl_xor(pa, 1);
        if ((lane & 1) == 0)
            *(__half2*)(ph + (size_t)node * 64 + lane) = __floats2half2_rn(pa, po);
    }
}

// ---------------- agg1: h1 = relu(mean-gather(p) + q)  [pure gather, no LDS] ----------------
// one node per wave; lane = (edge-slot 0..7, 16B channel-group 0..7); 1KB/wave-load.
__global__ __launch_bounds__(256) void k_agg1(const int* __restrict__ off,
                                              const int* __restrict__ esrc,
                                              const __half* __restrict__ ph,
                                              const float* __restrict__ q,
                                              float* __restrict__ h1) {
    int wv = threadIdx.x >> 6, lane = threadIdx.x & 63;
    int node = blockIdx.x * 4 + wv;          // N % 4 == 0
    int s0 = off[node];
    int s1 = (node == N_NODES - 1) ? N_EDGES : off[node + 1];
    int eg = lane >> 3;                       // 0..7
    int cg = lane & 7;                        // halves cg*8 .. cg*8+7
    float a[8] = {0, 0, 0, 0, 0, 0, 0, 0};
    float c2[8] = {0, 0, 0, 0, 0, 0, 0, 0};
    for (int i = s0; i < s1; i += 16) {
        int i0 = i + eg, i1 = i + 8 + eg;
        if (i0 < s1) {
            float4 rv = *(const float4*)(ph + (size_t)esrc[i0] * 64 + (cg << 3));
            const __half2* hp = (const __half2*)&rv;
            float2 f0 = __half22float2(hp[0]), f1 = __half22float2(hp[1]);
            float2 f2 = __half22float2(hp[2]), f3 = __half22float2(hp[3]);
            a[0] += f0.x; a[1] += f0.y; a[2] += f1.x; a[3] += f1.y;
            a[4] += f2.x; a[5] += f2.y; a[6] += f3.x; a[7] += f3.y;
        }
        if (i1 < s1) {
            float4 rv = *(const float4*)(ph + (size_t)esrc[i1] * 64 + (cg << 3));
            const __half2* hp = (const __half2*)&rv;
            float2 f0 = __half22float2(hp[0]), f1 = __half22float2(hp[1]);
            float2 f2 = __half22float2(hp[2]), f3 = __half22float2(hp[3]);
            c2[0] += f0.x; c2[1] += f0.y; c2[2] += f1.x; c2[3] += f1.y;
            c2[4] += f2.x; c2[5] += f2.y; c2[6] += f3.x; c2[7] += f3.y;
        }
    }
#pragma unroll
    for (int j = 0; j < 8; ++j) a[j] += c2[j];
#pragma unroll
    for (int j = 0; j < 8; ++j) {
        a[j] += __shfl_xor(a[j], 8);
        a[j] += __shfl_xor(a[j], 16);
        a[j] += __shfl_xor(a[j], 32);
    }
    if (eg == 0) {
        float inv = 1.0f / fmaxf((float)(s1 - s0), 1.0f);
        const float4* qp = (const float4*)(q + (size_t)node * 64 + (cg << 3));
        float4 q0 = qp[0], q1 = qp[1];
        float4 o0, o1;
        o0.x = fmaxf(fmaf(a[0], inv, q0.x), 0.f);
        o0.y = fmaxf(fmaf(a[1], inv, q0.y), 0.f);
        o0.z = fmaxf(fmaf(a[2], inv, q0.z), 0.f);
        o0.w = fmaxf(fmaf(a[3], inv, q0.w), 0.f);
        o1.x = fmaxf(fmaf(a[4], inv, q1.x), 0.f);
        o1.y = fmaxf(fmaf(a[5], inv, q1.y), 0.f);
        o1.z = fmaxf(fmaf(a[6], inv, q1.z), 0.f);
        o1.w = fmaxf(fmaf(a[7], inv, q1.w), 0.f);
        float4* op = (float4*)(h1 + (size_t)node * 64 + (cg << 3));
        op[0] = o0; op[1] = o1;
    }
}

// ---------------- pre2: z = h1@w2l (fp16), r = h1@w2r + b2 (fp32) ----------------
__global__ __launch_bounds__(256) void k_pre2(const float* __restrict__ h1,
                                              const float* __restrict__ w2l,
                                              const float* __restrict__ w2r,
                                              const float* __restrict__ b2,
                                              __half* __restrict__ zh,
                                              float* __restrict__ r) {
    int wv = threadIdx.x >> 6, lane = threadIdx.x & 63;
    int gw = blockIdx.x * 4 + wv;
    if (gw >= NWAVES_PRE) return;
    int c = lane & 31;
    bool isZ = lane < 32;
    const float* wm = isZ ? w2l : w2r;
    float wc[64];
#pragma unroll
    for (int k = 0; k < 64; ++k) wc[k] = wm[k * 32 + c];
    float bv = isZ ? 0.f : b2[c];
    int n0 = gw * NPW;
    for (int nn = 0; nn < NPW; ++nn) {
        int node = n0 + nn;
        float v = h1[(size_t)node * 64 + lane];
        float acc = bv;
#pragma unroll
        for (int k = 0; k < 64; ++k) acc = fmaf(__shfl(v, k), wc[k], acc);
        float ao = __shfl_xor(acc, 1);
        if (isZ) {
            if ((lane & 1) == 0)
                *(__half2*)(zh + (size_t)node * 32 + c) = __floats2half2_rn(acc, ao);
        } else {
            r[(size_t)node * 32 + c] = acc;
        }
    }
}

// ---------------- agg2 + classifier: fully in-register, no LDS ----------------
// one node per wave; lane = (edge-slot 0..15, 16B group 0..3).
__global__ __launch_bounds__(256) void k_agg2cls(const int* __restrict__ off,
                                                 const int* __restrict__ esrc,
                                                 const __half* __restrict__ zh,
                                                 const float* __restrict__ r,
                                                 const float* __restrict__ wc1,
                                                 const float* __restrict__ bc1,
                                                 const float* __restrict__ wc2,
                                                 const float* __restrict__ bc2,
                                                 float* __restrict__ out) {
    int wv = threadIdx.x >> 6, lane = threadIdx.x & 63;
    int node = blockIdx.x * 4 + wv;          // N % 4 == 0
    // classifier weights into registers
    float w1c[32];
    float b1v = 0.f;
    if (lane < 16) {
#pragma unroll
        for (int k = 0; k < 32; ++k) w1c[k] = wc1[k * 16 + lane];
        b1v = bc1[lane];
    }
    float w2v[16];
    float b2v = 0.f;
    if (lane < 2) {
#pragma unroll
        for (int k = 0; k < 16; ++k) w2v[k] = wc2[k * 2 + lane];
        b2v = bc2[lane];
    }
    int s0 = off[node];
    int s1 = (node == N_NODES - 1) ? N_EDGES : off[node + 1];
    int eg = lane >> 2;                       // 0..15
    int cg = lane & 3;                        // halves cg*8 .. cg*8+7
    float a[8] = {0, 0, 0, 0, 0, 0, 0, 0};
    for (int i = s0; i < s1; i += 32) {
        int i0 = i + eg, i1 = i + 16 + eg;
        if (i0 < s1) {
            float4 rv = *(const float4*)(zh + (size_t)esrc[i0] * 32 + (cg << 3));
            const __half2* hp = (const __half2*)&rv;
            float2 f0 = __half22float2(hp[0]), f1 = __half22float2(hp[1]);
            float2 f2 = __half22float2(hp[2]), f3 = __half22float2(hp[3]);
            a[0] += f0.x; a[1] += f0.y; a[2] += f1.x; a[3] += f1.y;
            a[4] += f2.x; a[5] += f2.y; a[6] += f3.x; a[7] += f3.y;
        }
        if (i1 < s1) {
            float4 rv = *(const float4*)(zh + (size_t)esrc[i1] * 32 + (cg << 3));
            const __half2* hp = (const __half2*)&rv;
            float2 f0 = __half22float2(hp[0]), f1 = __half22float2(hp[1]);
            float2 f2 = __half22float2(hp[2]), f3 = __half22float2(hp[3]);
            a[0] += f0.x; a[1] += f0.y; a[2] += f1.x; a[3] += f1.y;
            a[4] += f2.x; a[5] += f2.y; a[6] += f3.x; a[7] += f3.y;
        }
    }
#pragma unroll
    for (int j = 0; j < 8; ++j) {
        a[j] += __shfl_xor(a[j], 4);
        a[j] += __shfl_xor(a[j], 8);
        a[j] += __shfl_xor(a[j], 16);
        a[j] += __shfl_xor(a[j], 32);
    }
    // every lane now holds the full sums for its cg class; add r, relu
    float inv = 1.0f / fmaxf((float)(s1 - s0), 1.0f);
    const float4* rp = (const float4*)(r + (size_t)node * 32 + (cg << 3));
    float4 r0 = rp[0], r1 = rp[1];
    float h2l[8];
    h2l[0] = fmaxf(fmaf(a[0], inv, r0.x), 0.f);
    h2l[1] = fmaxf(fmaf(a[1], inv, r0.y), 0.f);
    h2l[2] = fmaxf(fmaf(a[2], inv, r0.z), 0.f);
    h2l[3] = fmaxf(fmaf(a[3], inv, r0.w), 0.f);
    h2l[4] = fmaxf(fmaf(a[4], inv, r1.x), 0.f);
    h2l[5] = fmaxf(fmaf(a[5], inv, r1.y), 0.f);
    h2l[6] = fmaxf(fmaf(a[6], inv, r1.z), 0.f);
    h2l[7] = fmaxf(fmaf(a[7], inv, r1.w), 0.f);
    // broadcast full h2 row to all lanes (source lane c>>3 has cg == c>>3)
    float h2f[32];
#pragma unroll
    for (int c = 0; c < 32; ++c) h2f[c] = __shfl(h2l[c & 7], c >> 3);
    // MLP1 on lanes 0..15
    float a1 = b1v;
#pragma unroll
    for (int k = 0; k < 32; ++k) a1 = fmaf(h2f[k], w1c[k], a1);
    a1 = fmaxf(a1, 0.f);
    // MLP2 on lanes 0..1 (shuffles executed by all lanes)
    float o = b2v;
#pragma unroll
    for (int k = 0; k < 16; ++k) {
        float h3k = __shfl(a1, k);
        o = fmaf(h3k, w2v[k], o);
    }
    float o1 = __shfl(o, 1);
    if (lane == 0) *(float2*)(out + (size_t)node * 2) = make_float2(o, o1);
}

extern "C" void kernel_launch(void* const* d_in, const int* in_sizes, int n_in,
                              void* d_out, int out_size, void* d_ws, size_t ws_size,
                              hipStream_t stream) {
    const float* x   = (const float*)d_in[0];
    const int*   ei  = (const int*)d_in[1];
    const int*   src = ei;
    const int*   dst = ei + N_EDGES;
    const float* w1l = (const float*)d_in[2];
    const float* w1r = (const float*)d_in[3];
    const float* b1  = (const float*)d_in[4];
    const float* w2l = (const float*)d_in[5];
    const float* w2r = (const float*)d_in[6];
    const float* b2  = (const float*)d_in[7];
    const float* wc1 = (const float*)d_in[8];
    const float* bc1 = (const float*)d_in[9];
    const float* wc2 = (const float*)d_in[10];
    const float* bc2 = (const float*)d_in[11];
    float* out = (float*)d_out;

    // ws layout (4B units):
    //   bincnt[400] | binoff[400] | bincur[400] | off[N] | binned[E] | esrc[E]
    //   | h1[64N] | q[64N] (reused: zh[16N]+r[32N]) | ph[32N]
    int*   wi     = (int*)d_ws;
    int*   bincnt = wi;
    int*   binoff = wi + 400;
    int*   bincur = wi + 800;
    int*   off    = wi + 1200;
    int*   binned = off + N_NODES;
    int*   esrc   = binned + N_EDGES;
    float* h1     = (float*)(esrc + N_EDGES);
    float* q      = h1 + (size_t)64 * N_NODES;
    float* phf    = q + (size_t)64 * N_NODES;
    __half* ph    = (__half*)phf;
    __half* zh    = (__half*)q;                       // overlay: q dead after agg1
    float*  r     = q + (size_t)16 * N_NODES;

    // ---- CSR build ----
    hipMemsetAsync(bincnt, 0, 400 * sizeof(int), stream);
    k_bhist<<<NBLK_E, 256, 0, stream>>>(dst, bincnt);
    k_bscan<<<1, 512, 0, stream>>>(bincnt, binoff, bincur);
    k_binA<<<NBLK_E, 256, 0, stream>>>(src, dst, bincur, binned);
    k_binB<<<NBINS, 256, 0, stream>>>(binoff, binned, off, esrc);

    // ---- layer 1 ----
    k_pre1<<<(NWAVES_PRE + 3) / 4, 256, 0, stream>>>(x, w1l, w1r, b1, ph, q);
    k_agg1<<<N_NODES / 4, 256, 0, stream>>>(off, esrc, ph, q, h1);

    // ---- layer 2 + classifier ----
    k_pre2<<<(NWAVES_PRE + 3) / 4, 256, 0, stream>>>(h1, w2l, w2r, b2, zh, r);
    k_agg2cls<<<N_NODES / 4, 256, 0, stream>>>(off, esrc, zh, r, wc1, bc1, wc2, bc2, out);
}

// Round 6
// 270.990 us; speedup vs baseline: 1.0529x; 1.0529x over previous
//
#include <hip/hip_runtime.h>
#include <hip/hip_fp16.h>

#define N_NODES 50000
#define N_EDGES 800000
#define NBINS   391          // ceil(50000/128), 128 dst nodes per bin
#define EPB     4096         // edges per block (bhist / binA)
#define NBLK_E  ((N_EDGES + EPB - 1) / EPB)
#define MAXSEG  4096         // pass-B LDS segment capacity (mean 2046)
#define NPW     8            // nodes per wave in pre-GEMM kernels
#define NWAVES_PRE (N_NODES / NPW)   // 6250

// ---------------- bin-level histogram ----------------
__global__ void k_bhist(const int* __restrict__ dst, int* __restrict__ bincnt) {
    __shared__ int cnt[NBINS];
    int t = threadIdx.x;
    for (int i = t; i < NBINS; i += 256) cnt[i] = 0;
    __syncthreads();
    int base = blockIdx.x * EPB;
    int nE = min(EPB, N_EDGES - base);
    for (int i = t; i < nE; i += 256) atomicAdd(&cnt[dst[base + i] >> 7], 1);
    __syncthreads();
    for (int i = t; i < NBINS; i += 256) if (cnt[i]) atomicAdd(&bincnt[i], cnt[i]);
}

// ---------------- exclusive scan of bin counts ----------------
__global__ void k_bscan(const int* __restrict__ bincnt, int* __restrict__ binoff,
                        int* __restrict__ bincur) {
    __shared__ int tmp[512];
    int t = threadIdx.x;
    int v = (t < NBINS) ? bincnt[t] : 0;
    tmp[t] = v;
    __syncthreads();
    int val = v;
    for (int d = 1; d < 512; d <<= 1) {
        int add = (t >= d) ? tmp[t - d] : 0;
        __syncthreads();
        val += add;
        tmp[t] = val;
        __syncthreads();
    }
    if (t < NBINS) { binoff[t] = val - v; bincur[t] = val - v; }
    if (t == NBINS - 1) binoff[NBINS] = val;
}

// ---------------- pass A: LDS-staged bin scatter ----------------
__global__ void k_binA(const int* __restrict__ src, const int* __restrict__ dst,
                       int* __restrict__ bincur, int* __restrict__ binned) {
    __shared__ int cnt[NBINS];
    __shared__ int sc[512];          // inclusive-scan workspace
    __shared__ int lpos[NBINS];
    __shared__ int base[NBINS];
    __shared__ int stage[EPB];
    __shared__ unsigned short sbin[EPB];
    int t = threadIdx.x;
    int blkbase = blockIdx.x * EPB;
    int nE = min(EPB, N_EDGES - blkbase);
    for (int i = t; i < NBINS; i += 256) cnt[i] = 0;
    __syncthreads();
    int sv[16], dv[16];
#pragma unroll
    for (int k = 0; k < 16; ++k) {
        int e = blkbase + t + k * 256;
        if (e < N_EDGES) {
            sv[k] = src[e];
            dv[k] = dst[e];
            atomicAdd(&cnt[dv[k] >> 7], 1);
        } else dv[k] = -1;
    }
    __syncthreads();
    // parallel inclusive scan of 391 counts (2 slots/thread, Hillis-Steele)
    sc[t]       = (t < NBINS) ? cnt[t] : 0;
    sc[t + 256] = (t + 256 < NBINS) ? cnt[t + 256] : 0;
    __syncthreads();
    for (int d = 1; d < 512; d <<= 1) {
        int s0 = t, s1 = t + 256;
        int n0 = sc[s0] + ((s0 >= d) ? sc[s0 - d] : 0);
        int n1 = sc[s1] + ((s1 >= d) ? sc[s1 - d] : 0);
        __syncthreads();
        sc[s0] = n0; sc[s1] = n1;
        __syncthreads();
    }
    // exclusive offset within block = inclusive - own count
    for (int b = t; b < NBINS; b += 256) {
        int excl = sc[b] - cnt[b];
        lpos[b] = excl;
        sc[b] = excl;                     // keep exclusive for final write pass
        if (cnt[b] > 0) base[b] = atomicAdd(&bincur[b], cnt[b]);
    }
    __syncthreads();
#pragma unroll
    for (int k = 0; k < 16; ++k) {
        if (dv[k] >= 0) {
            int b = dv[k] >> 7;
            int p = atomicAdd(&lpos[b], 1);
            stage[p] = (sv[k] & 0xFFFF) | ((dv[k] & 127) << 16);
            sbin[p] = (unsigned short)b;
        }
    }
    __syncthreads();
    for (int i = t; i < nE; i += 256) {
        int b = sbin[i];
        binned[base[b] + (i - sc[b])] = stage[i];
    }
}

// ---------------- pass B: per-bin counting sort; derives off[] ----------------
__global__ void k_binB(const int* __restrict__ binoff, const int* __restrict__ binned,
                       int* __restrict__ off, int* __restrict__ esrc) {
    __shared__ int cnt[128];
    __shared__ int tmp[128];
    __shared__ int cur[128];
    __shared__ int buf[MAXSEG];
    int b = blockIdx.x, t = threadIdx.x;
    int n0 = b << 7;
    int seg0 = binoff[b], seg1 = binoff[b + 1];
    int n = seg1 - seg0;
    if (t < 128) cnt[t] = 0;
    __syncthreads();
    for (int i = t; i < n; i += 256) atomicAdd(&cnt[binned[seg0 + i] >> 16], 1);
    __syncthreads();
    int v = (t < 128) ? cnt[t] : 0;
    if (t < 128) tmp[t] = v;
    __syncthreads();
    int val = v;
    for (int d = 1; d < 128; d <<= 1) {
        int add = (t >= d && t < 128) ? tmp[t - d] : 0;
        __syncthreads();
        if (t < 128) { val += add; tmp[t] = val; }
        __syncthreads();
    }
    if (t < 128) {
        int excl = val - v;
        cur[t] = excl;
        int node = n0 + t;
        if (node < N_NODES) off[node] = seg0 + excl;
    }
    __syncthreads();
    if (n <= MAXSEG) {
        for (int i = t; i < n; i += 256) {
            int w = binned[seg0 + i];
            int p = atomicAdd(&cur[w >> 16], 1);
            buf[p] = w & 0xFFFF;
        }
        __syncthreads();
        for (int i = t; i < n; i += 256) esrc[seg0 + i] = buf[i];
    } else {
        for (int i = t; i < n; i += 256) {
            int w = binned[seg0 + i];
            int p = atomicAdd(&cur[w >> 16], 1);
            esrc[seg0 + p] = w & 0xFFFF;
        }
    }
}

// ---------------- pre1: p = x@w1l (fp16), q = x@w1r + b1 (fp32) ----------------
// register-resident weight columns + shuffle row-broadcast; no LDS.
__global__ __launch_bounds__(256) void k_pre1(const float* __restrict__ x,
                                              const float* __restrict__ wl,
                                              const float* __restrict__ wr,
                                              const float* __restrict__ b,
                                              __half* __restrict__ ph,
                                              float* __restrict__ q) {
    int wv = threadIdx.x >> 6, lane = threadIdx.x & 63;
    int gw = blockIdx.x * 4 + wv;
    if (gw >= NWAVES_PRE) return;
    float wlc[64], wrc[64];
#pragma unroll
    for (int k = 0; k < 64; ++k) { wlc[k] = wl[k * 64 + lane]; wrc[k] = wr[k * 64 + lane]; }
    float bv = b[lane];
    int n0 = gw * NPW;
    for (int nn = 0; nn < NPW; ++nn) {
        int node = n0 + nn;
        float v = x[(size_t)node * 64 + lane];
        float pa = 0.f, qa = bv;
#pragma unroll
        for (int k = 0; k < 64; ++k) {
            float xk = __shfl(v, k);
            pa = fmaf(xk, wlc[k], pa);
            qa = fmaf(xk, wrc[k], qa);
        }
        q[(size_t)node * 64 + lane] = qa;
        float po = __shfl_xor(pa, 1);
        if ((lane & 1) == 0)
            *(__half2*)(ph + (size_t)node * 64 + lane) = __floats2half2_rn(pa, po);
    }
}

// ---------------- agg1: h1 = relu(mean-gather(p) + q)  [pure gather, no LDS] ----------------
__global__ __launch_bounds__(256) void k_agg1(const int* __restrict__ off,
                                              const int* __restrict__ esrc,
                                              const __half* __restrict__ ph,
                                              const float* __restrict__ q,
                                              float* __restrict__ h1) {
    int wv = threadIdx.x >> 6, lane = threadIdx.x & 63;
    int node = blockIdx.x * 4 + wv;          // N % 4 == 0
    int s0 = off[node];
    int s1 = (node == N_NODES - 1) ? N_EDGES : off[node + 1];
    int eg = lane >> 3;                       // 0..7
    int cg = lane & 7;                        // halves cg*8 .. cg*8+7
    float a[8] = {0, 0, 0, 0, 0, 0, 0, 0};
    float c2[8] = {0, 0, 0, 0, 0, 0, 0, 0};
    for (int i = s0; i < s1; i += 16) {
        int i0 = i + eg, i1 = i + 8 + eg;
        if (i0 < s1) {
            float4 rv = *(const float4*)(ph + (size_t)esrc[i0] * 64 + (cg << 3));
            const __half2* hp = (const __half2*)&rv;
            float2 f0 = __half22float2(hp[0]), f1 = __half22float2(hp[1]);
            float2 f2 = __half22float2(hp[2]), f3 = __half22float2(hp[3]);
            a[0] += f0.x; a[1] += f0.y; a[2] += f1.x; a[3] += f1.y;
            a[4] += f2.x; a[5] += f2.y; a[6] += f3.x; a[7] += f3.y;
        }
        if (i1 < s1) {
            float4 rv = *(const float4*)(ph + (size_t)esrc[i1] * 64 + (cg << 3));
            const __half2* hp = (const __half2*)&rv;
            float2 f0 = __half22float2(hp[0]), f1 = __half22float2(hp[1]);
            float2 f2 = __half22float2(hp[2]), f3 = __half22float2(hp[3]);
            c2[0] += f0.x; c2[1] += f0.y; c2[2] += f1.x; c2[3] += f1.y;
            c2[4] += f2.x; c2[5] += f2.y; c2[6] += f3.x; c2[7] += f3.y;
        }
    }
#pragma unroll
    for (int j = 0; j < 8; ++j) a[j] += c2[j];
#pragma unroll
    for (int j = 0; j < 8; ++j) {
        a[j] += __shfl_xor(a[j], 8);
        a[j] += __shfl_xor(a[j], 16);
        a[j] += __shfl_xor(a[j], 32);
    }
    if (eg == 0) {
        float inv = 1.0f / fmaxf((float)(s1 - s0), 1.0f);
        const float4* qp = (const float4*)(q + (size_t)node * 64 + (cg << 3));
        float4 q0 = qp[0], q1 = qp[1];
        float4 o0, o1;
        o0.x = fmaxf(fmaf(a[0], inv, q0.x), 0.f);
        o0.y = fmaxf(fmaf(a[1], inv, q0.y), 0.f);
        o0.z = fmaxf(fmaf(a[2], inv, q0.z), 0.f);
        o0.w = fmaxf(fmaf(a[3], inv, q0.w), 0.f);
        o1.x = fmaxf(fmaf(a[4], inv, q1.x), 0.f);
        o1.y = fmaxf(fmaf(a[5], inv, q1.y), 0.f);
        o1.z = fmaxf(fmaf(a[6], inv, q1.z), 0.f);
        o1.w = fmaxf(fmaf(a[7], inv, q1.w), 0.f);
        float4* op = (float4*)(h1 + (size_t)node * 64 + (cg << 3));
        op[0] = o0; op[1] = o1;
    }
}

// ---------------- pre2: z = h1@w2l (fp16), r = h1@w2r + b2 (fp32) ----------------
__global__ __launch_bounds__(256) void k_pre2(const float* __restrict__ h1,
                                              const float* __restrict__ w2l,
                                              const float* __restrict__ w2r,
                                              const float* __restrict__ b2,
                                              __half* __restrict__ zh,
                                              float* __restrict__ r) {
    int wv = threadIdx.x >> 6, lane = threadIdx.x & 63;
    int gw = blockIdx.x * 4 + wv;
    if (gw >= NWAVES_PRE) return;
    int c = lane & 31;
    bool isZ = lane < 32;
    const float* wm = isZ ? w2l : w2r;
    float wc[64];
#pragma unroll
    for (int k = 0; k < 64; ++k) wc[k] = wm[k * 32 + c];
    float bv = isZ ? 0.f : b2[c];
    int n0 = gw * NPW;
    for (int nn = 0; nn < NPW; ++nn) {
        int node = n0 + nn;
        float v = h1[(size_t)node * 64 + lane];
        float acc = bv;
#pragma unroll
        for (int k = 0; k < 64; ++k) acc = fmaf(__shfl(v, k), wc[k], acc);
        float ao = __shfl_xor(acc, 1);
        if (isZ) {
            if ((lane & 1) == 0)
                *(__half2*)(zh + (size_t)node * 32 + c) = __floats2half2_rn(acc, ao);
        } else {
            r[(size_t)node * 32 + c] = acc;
        }
    }
}

// ---------------- agg2 + classifier: fully in-register, no LDS ----------------
__global__ __launch_bounds__(256) void k_agg2cls(const int* __restrict__ off,
                                                 const int* __restrict__ esrc,
                                                 const __half* __restrict__ zh,
                                                 const float* __restrict__ r,
                                                 const float* __restrict__ wc1,
                                                 const float* __restrict__ bc1,
                                                 const float* __restrict__ wc2,
                                                 const float* __restrict__ bc2,
                                                 float* __restrict__ out) {
    int wv = threadIdx.x >> 6, lane = threadIdx.x & 63;
    int node = blockIdx.x * 4 + wv;          // N % 4 == 0
    float w1c[32];
    float b1v = 0.f;
    if (lane < 16) {
#pragma unroll
        for (int k = 0; k < 32; ++k) w1c[k] = wc1[k * 16 + lane];
        b1v = bc1[lane];
    }
    float w2v[16];
    float b2v = 0.f;
    if (lane < 2) {
#pragma unroll
        for (int k = 0; k < 16; ++k) w2v[k] = wc2[k * 2 + lane];
        b2v = bc2[lane];
    }
    int s0 = off[node];
    int s1 = (node == N_NODES - 1) ? N_EDGES : off[node + 1];
    int eg = lane >> 2;                       // 0..15
    int cg = lane & 3;                        // halves cg*8 .. cg*8+7
    float a[8] = {0, 0, 0, 0, 0, 0, 0, 0};
    for (int i = s0; i < s1; i += 32) {
        int i0 = i + eg, i1 = i + 16 + eg;
        if (i0 < s1) {
            float4 rv = *(const float4*)(zh + (size_t)esrc[i0] * 32 + (cg << 3));
            const __half2* hp = (const __half2*)&rv;
            float2 f0 = __half22float2(hp[0]), f1 = __half22float2(hp[1]);
            float2 f2 = __half22float2(hp[2]), f3 = __half22float2(hp[3]);
            a[0] += f0.x; a[1] += f0.y; a[2] += f1.x; a[3] += f1.y;
            a[4] += f2.x; a[5] += f2.y; a[6] += f3.x; a[7] += f3.y;
        }
        if (i1 < s1) {
            float4 rv = *(const float4*)(zh + (size_t)esrc[i1] * 32 + (cg << 3));
            const __half2* hp = (const __half2*)&rv;
            float2 f0 = __half22float2(hp[0]), f1 = __half22float2(hp[1]);
            float2 f2 = __half22float2(hp[2]), f3 = __half22float2(hp[3]);
            a[0] += f0.x; a[1] += f0.y; a[2] += f1.x; a[3] += f1.y;
            a[4] += f2.x; a[5] += f2.y; a[6] += f3.x; a[7] += f3.y;
        }
    }
#pragma unroll
    for (int j = 0; j < 8; ++j) {
        a[j] += __shfl_xor(a[j], 4);
        a[j] += __shfl_xor(a[j], 8);
        a[j] += __shfl_xor(a[j], 16);
        a[j] += __shfl_xor(a[j], 32);
    }
    float inv = 1.0f / fmaxf((float)(s1 - s0), 1.0f);
    const float4* rp = (const float4*)(r + (size_t)node * 32 + (cg << 3));
    float4 r0 = rp[0], r1 = rp[1];
    float h2l[8];
    h2l[0] = fmaxf(fmaf(a[0], inv, r0.x), 0.f);
    h2l[1] = fmaxf(fmaf(a[1], inv, r0.y), 0.f);
    h2l[2] = fmaxf(fmaf(a[2], inv, r0.z), 0.f);
    h2l[3] = fmaxf(fmaf(a[3], inv, r0.w), 0.f);
    h2l[4] = fmaxf(fmaf(a[4], inv, r1.x), 0.f);
    h2l[5] = fmaxf(fmaf(a[5], inv, r1.y), 0.f);
    h2l[6] = fmaxf(fmaf(a[6], inv, r1.z), 0.f);
    h2l[7] = fmaxf(fmaf(a[7], inv, r1.w), 0.f);
    float h2f[32];
#pragma unroll
    for (int c = 0; c < 32; ++c) h2f[c] = __shfl(h2l[c & 7], c >> 3);
    float a1 = b1v;
#pragma unroll
    for (int k = 0; k < 32; ++k) a1 = fmaf(h2f[k], w1c[k], a1);
    a1 = fmaxf(a1, 0.f);
    float o = b2v;
#pragma unroll
    for (int k = 0; k < 16; ++k) {
        float h3k = __shfl(a1, k);
        o = fmaf(h3k, w2v[k], o);
    }
    float o1 = __shfl(o, 1);
    if (lane == 0) *(float2*)(out + (size_t)node * 2) = make_float2(o, o1);
}

extern "C" void kernel_launch(void* const* d_in, const int* in_sizes, int n_in,
                              void* d_out, int out_size, void* d_ws, size_t ws_size,
                              hipStream_t stream) {
    const float* x   = (const float*)d_in[0];
    const int*   ei  = (const int*)d_in[1];
    const int*   src = ei;
    const int*   dst = ei + N_EDGES;
    const float* w1l = (const float*)d_in[2];
    const float* w1r = (const float*)d_in[3];
    const float* b1  = (const float*)d_in[4];
    const float* w2l = (const float*)d_in[5];
    const float* w2r = (const float*)d_in[6];
    const float* b2  = (const float*)d_in[7];
    const float* wc1 = (const float*)d_in[8];
    const float* bc1 = (const float*)d_in[9];
    const float* wc2 = (const float*)d_in[10];
    const float* bc2 = (const float*)d_in[11];
    float* out = (float*)d_out;

    // ws layout (4B units):
    //   bincnt[400] | binoff[400] | bincur[400] | off[N] | binned[E] | esrc[E]
    //   | h1[64N] | q[64N] (reused: zh[16N]+r[32N]) | ph[32N]
    int*   wi     = (int*)d_ws;
    int*   bincnt = wi;
    int*   binoff = wi + 400;
    int*   bincur = wi + 800;
    int*   off    = wi + 1200;
    int*   binned = off + N_NODES;
    int*   esrc   = binned + N_EDGES;
    float* h1     = (float*)(esrc + N_EDGES);
    float* q      = h1 + (size_t)64 * N_NODES;
    float* phf    = q + (size_t)64 * N_NODES;
    __half* ph    = (__half*)phf;
    __half* zh    = (__half*)q;                       // overlay: q dead after agg1
    float*  r     = q + (size_t)16 * N_NODES;

    // ---- CSR build ----
    hipMemsetAsync(bincnt, 0, 400 * sizeof(int), stream);
    k_bhist<<<NBLK_E, 256, 0, stream>>>(dst, bincnt);
    k_bscan<<<1, 512, 0, stream>>>(bincnt, binoff, bincur);
    k_binA<<<NBLK_E, 256, 0, stream>>>(src, dst, bincur, binned);
    k_binB<<<NBINS, 256, 0, stream>>>(binoff, binned, off, esrc);

    // ---- layer 1 ----
    k_pre1<<<(NWAVES_PRE + 3) / 4, 256, 0, stream>>>(x, w1l, w1r, b1, ph, q);
    k_agg1<<<N_NODES / 4, 256, 0, stream>>>(off, esrc, ph, q, h1);

    // ---- layer 2 + classifier ----
    k_pre2<<<(NWAVES_PRE + 3) / 4, 256, 0, stream>>>(h1, w2l, w2r, b2, zh, r);
    k_agg2cls<<<N_NODES / 4, 256, 0, stream>>>(off, esrc, zh, r, wc1, bc1, wc2, bc2, out);
}

// Round 8
// 250.479 us; speedup vs baseline: 1.1391x; 1.0819x over previous
//
#include <hip/hip_runtime.h>
#include <hip/hip_fp16.h>

#define N_NODES 50000
#define N_EDGES 800000
#define NBINS   391          // ceil(50000/128), 128 dst nodes per bin
#define EPB     4096         // edges per block (bhist / binA)
#define NBLK_E  ((N_EDGES + EPB - 1) / EPB)
#define MAXSEG  4096         // pass-B LDS segment capacity (mean 2046)
#define NGRP    196          // ceil(50000/256) node groups for pre kernels

// ---------------- bin-level histogram ----------------
__global__ void k_bhist(const int* __restrict__ dst, int* __restrict__ bincnt) {
    __shared__ int cnt[NBINS];
    int t = threadIdx.x;
    for (int i = t; i < NBINS; i += 256) cnt[i] = 0;
    __syncthreads();
    int base = blockIdx.x * EPB;
    int nE = min(EPB, N_EDGES - base);
    for (int i = t; i < nE; i += 256) atomicAdd(&cnt[dst[base + i] >> 7], 1);
    __syncthreads();
    for (int i = t; i < NBINS; i += 256) if (cnt[i]) atomicAdd(&bincnt[i], cnt[i]);
}

// ---------------- exclusive scan of bin counts ----------------
__global__ void k_bscan(const int* __restrict__ bincnt, int* __restrict__ binoff,
                        int* __restrict__ bincur) {
    __shared__ int tmp[512];
    int t = threadIdx.x;
    int v = (t < NBINS) ? bincnt[t] : 0;
    tmp[t] = v;
    __syncthreads();
    int val = v;
    for (int d = 1; d < 512; d <<= 1) {
        int add = (t >= d) ? tmp[t - d] : 0;
        __syncthreads();
        val += add;
        tmp[t] = val;
        __syncthreads();
    }
    if (t < NBINS) { binoff[t] = val - v; bincur[t] = val - v; }
    if (t == NBINS - 1) binoff[NBINS] = val;
}

// ---------------- pass A: LDS-staged bin scatter ----------------
__global__ void k_binA(const int* __restrict__ src, const int* __restrict__ dst,
                       int* __restrict__ bincur, int* __restrict__ binned) {
    __shared__ int cnt[NBINS];
    __shared__ int sc[512];
    __shared__ int lpos[NBINS];
    __shared__ int base[NBINS];
    __shared__ int stage[EPB];
    __shared__ unsigned short sbin[EPB];
    int t = threadIdx.x;
    int blkbase = blockIdx.x * EPB;
    int nE = min(EPB, N_EDGES - blkbase);
    for (int i = t; i < NBINS; i += 256) cnt[i] = 0;
    __syncthreads();
    int sv[16], dv[16];
#pragma unroll
    for (int k = 0; k < 16; ++k) {
        int e = blkbase + t + k * 256;
        if (e < N_EDGES) {
            sv[k] = src[e];
            dv[k] = dst[e];
            atomicAdd(&cnt[dv[k] >> 7], 1);
        } else dv[k] = -1;
    }
    __syncthreads();
    sc[t]       = (t < NBINS) ? cnt[t] : 0;
    sc[t + 256] = (t + 256 < NBINS) ? cnt[t + 256] : 0;
    __syncthreads();
    for (int d = 1; d < 512; d <<= 1) {
        int s0 = t, s1 = t + 256;
        int n0 = sc[s0] + ((s0 >= d) ? sc[s0 - d] : 0);
        int n1 = sc[s1] + ((s1 >= d) ? sc[s1 - d] : 0);
        __syncthreads();
        sc[s0] = n0; sc[s1] = n1;
        __syncthreads();
    }
    for (int b = t; b < NBINS; b += 256) {
        int excl = sc[b] - cnt[b];
        lpos[b] = excl;
        sc[b] = excl;
        if (cnt[b] > 0) base[b] = atomicAdd(&bincur[b], cnt[b]);
    }
    __syncthreads();
#pragma unroll
    for (int k = 0; k < 16; ++k) {
        if (dv[k] >= 0) {
            int b = dv[k] >> 7;
            int p = atomicAdd(&lpos[b], 1);
            stage[p] = (sv[k] & 0xFFFF) | ((dv[k] & 127) << 16);
            sbin[p] = (unsigned short)b;
        }
    }
    __syncthreads();
    for (int i = t; i < nE; i += 256) {
        int b = sbin[i];
        binned[base[b] + (i - sc[b])] = stage[i];
    }
}

// ---------------- pass B: per-bin counting sort; derives off[] ----------------
__global__ void k_binB(const int* __restrict__ binoff, const int* __restrict__ binned,
                       int* __restrict__ off, int* __restrict__ esrc) {
    __shared__ int cnt[128];
    __shared__ int tmp[128];
    __shared__ int cur[128];
    __shared__ int buf[MAXSEG];
    int b = blockIdx.x, t = threadIdx.x;
    int n0 = b << 7;
    int seg0 = binoff[b], seg1 = binoff[b + 1];
    int n = seg1 - seg0;
    if (t < 128) cnt[t] = 0;
    __syncthreads();
    for (int i = t; i < n; i += 256) atomicAdd(&cnt[binned[seg0 + i] >> 16], 1);
    __syncthreads();
    int v = (t < 128) ? cnt[t] : 0;
    if (t < 128) tmp[t] = v;
    __syncthreads();
    int val = v;
    for (int d = 1; d < 128; d <<= 1) {
        int add = (t >= d && t < 128) ? tmp[t - d] : 0;
        __syncthreads();
        if (t < 128) { val += add; tmp[t] = val; }
        __syncthreads();
    }
    if (t < 128) {
        int excl = val - v;
        cur[t] = excl;
        int node = n0 + t;
        if (node < N_NODES) off[node] = seg0 + excl;
    }
    __syncthreads();
    if (n <= MAXSEG) {
        for (int i = t; i < n; i += 256) {
            int w = binned[seg0 + i];
            int p = atomicAdd(&cur[w >> 16], 1);
            buf[p] = w & 0xFFFF;
        }
        __syncthreads();
        for (int i = t; i < n; i += 256) esrc[seg0 + i] = buf[i];
    } else {
        for (int i = t; i < n; i += 256) {
            int w = binned[seg0 + i];
            int p = atomicAdd(&cur[w >> 16], 1);
            esrc[seg0 + p] = w & 0xFFFF;
        }
    }
}

// ---------------- pre1: p = x@w1l (fp16), q = x@w1r + b1 (fp32) ----------------
// lane = node; weights are wave-uniform (role from blockIdx) -> SGPR operands,
// pure VALU, zero DS ops. Block = 256 nodes x 32 outputs of one role.
__global__ __launch_bounds__(256) void k_pre1(const float* __restrict__ x,
                                              const float* __restrict__ wl,
                                              const float* __restrict__ wr,
                                              const float* __restrict__ b,
                                              __half* __restrict__ ph,
                                              float* __restrict__ q) {
    int role = blockIdx.x & 3;                    // scalar by construction
    int wsel = role >> 1;
    int c0 = (role & 1) * 32;
    int node = (blockIdx.x >> 2) * 256 + threadIdx.x;
    bool valid = node < N_NODES;
    float xr[64];
    const float4* xp = (const float4*)(x + (size_t)node * 64);
#pragma unroll
    for (int i = 0; i < 16; ++i) {
        float4 v = valid ? xp[i] : make_float4(0.f, 0.f, 0.f, 0.f);
        xr[4 * i + 0] = v.x; xr[4 * i + 1] = v.y;
        xr[4 * i + 2] = v.z; xr[4 * i + 3] = v.w;
    }
    const float* __restrict__ wm = wsel ? wr : wl;
    float acc[32];
    if (wsel) {
#pragma unroll
        for (int c = 0; c < 32; ++c) acc[c] = b[c0 + c];
    } else {
#pragma unroll
        for (int c = 0; c < 32; ++c) acc[c] = 0.f;
    }
#pragma unroll
    for (int k = 0; k < 64; ++k) {
        float xk = xr[k];
#pragma unroll
        for (int c = 0; c < 32; ++c)
            acc[c] = fmaf(xk, wm[k * 64 + c0 + c], acc[c]);
    }
    if (!valid) return;
    if (wsel == 0) {
        alignas(16) __half2 hv[16];               // 32 halfs = 64 B = 4 float4
#pragma unroll
        for (int i = 0; i < 16; ++i)
            hv[i] = __floats2half2_rn(acc[2 * i], acc[2 * i + 1]);
        float4* op = (float4*)(ph + (size_t)node * 64 + c0);
#pragma unroll
        for (int i = 0; i < 4; ++i) op[i] = ((float4*)hv)[i];
    } else {
        float4* op = (float4*)(q + (size_t)node * 64 + c0);
#pragma unroll
        for (int i = 0; i < 8; ++i)
            op[i] = make_float4(acc[4 * i], acc[4 * i + 1], acc[4 * i + 2], acc[4 * i + 3]);
    }
}

// ---------------- agg1: h1 = relu(mean-gather(p) + q)  [pure gather, no LDS] ----------------
__global__ __launch_bounds__(256) void k_agg1(const int* __restrict__ off,
                                              const int* __restrict__ esrc,
                                              const __half* __restrict__ ph,
                                              const float* __restrict__ q,
                                              float* __restrict__ h1) {
    int wv = threadIdx.x >> 6, lane = threadIdx.x & 63;
    int node = blockIdx.x * 4 + wv;          // N % 4 == 0
    int s0 = off[node];
    int s1 = (node == N_NODES - 1) ? N_EDGES : off[node + 1];
    int eg = lane >> 3;                       // 0..7
    int cg = lane & 7;                        // halves cg*8 .. cg*8+7
    float a[8] = {0, 0, 0, 0, 0, 0, 0, 0};
    float c2[8] = {0, 0, 0, 0, 0, 0, 0, 0};
    for (int i = s0; i < s1; i += 16) {
        int i0 = i + eg, i1 = i + 8 + eg;
        if (i0 < s1) {
            float4 rv = *(const float4*)(ph + (size_t)esrc[i0] * 64 + (cg << 3));
            const __half2* hp = (const __half2*)&rv;
            float2 f0 = __half22float2(hp[0]), f1 = __half22float2(hp[1]);
            float2 f2 = __half22float2(hp[2]), f3 = __half22float2(hp[3]);
            a[0] += f0.x; a[1] += f0.y; a[2] += f1.x; a[3] += f1.y;
            a[4] += f2.x; a[5] += f2.y; a[6] += f3.x; a[7] += f3.y;
        }
        if (i1 < s1) {
            float4 rv = *(const float4*)(ph + (size_t)esrc[i1] * 64 + (cg << 3));
            const __half2* hp = (const __half2*)&rv;
            float2 f0 = __half22float2(hp[0]), f1 = __half22float2(hp[1]);
            float2 f2 = __half22float2(hp[2]), f3 = __half22float2(hp[3]);
            c2[0] += f0.x; c2[1] += f0.y; c2[2] += f1.x; c2[3] += f1.y;
            c2[4] += f2.x; c2[5] += f2.y; c2[6] += f3.x; c2[7] += f3.y;
        }
    }
#pragma unroll
    for (int j = 0; j < 8; ++j) a[j] += c2[j];
#pragma unroll
    for (int j = 0; j < 8; ++j) {
        a[j] += __shfl_xor(a[j], 8);
        a[j] += __shfl_xor(a[j], 16);
        a[j] += __shfl_xor(a[j], 32);
    }
    if (eg == 0) {
        float inv = 1.0f / fmaxf((float)(s1 - s0), 1.0f);
        const float4* qp = (const float4*)(q + (size_t)node * 64 + (cg << 3));
        float4 q0 = qp[0], q1 = qp[1];
        float4 o0, o1;
        o0.x = fmaxf(fmaf(a[0], inv, q0.x), 0.f);
        o0.y = fmaxf(fmaf(a[1], inv, q0.y), 0.f);
        o0.z = fmaxf(fmaf(a[2], inv, q0.z), 0.f);
        o0.w = fmaxf(fmaf(a[3], inv, q0.w), 0.f);
        o1.x = fmaxf(fmaf(a[4], inv, q1.x), 0.f);
        o1.y = fmaxf(fmaf(a[5], inv, q1.y), 0.f);
        o1.z = fmaxf(fmaf(a[6], inv, q1.z), 0.f);
        o1.w = fmaxf(fmaf(a[7], inv, q1.w), 0.f);
        float4* op = (float4*)(h1 + (size_t)node * 64 + (cg << 3));
        op[0] = o0; op[1] = o1;
    }
}

// ---------------- pre2: z = h1@w2l (fp16), r = h1@w2r + b2 (fp32) ----------------
__global__ __launch_bounds__(256) void k_pre2(const float* __restrict__ h1,
                                              const float* __restrict__ w2l,
                                              const float* __restrict__ w2r,
                                              const float* __restrict__ b2,
                                              __half* __restrict__ zh,
                                              float* __restrict__ r) {
    int role = blockIdx.x & 1;
    int node = (blockIdx.x >> 1) * 256 + threadIdx.x;
    bool valid = node < N_NODES;
    float xr[64];
    const float4* xp = (const float4*)(h1 + (size_t)node * 64);
#pragma unroll
    for (int i = 0; i < 16; ++i) {
        float4 v = valid ? xp[i] : make_float4(0.f, 0.f, 0.f, 0.f);
        xr[4 * i + 0] = v.x; xr[4 * i + 1] = v.y;
        xr[4 * i + 2] = v.z; xr[4 * i + 3] = v.w;
    }
    const float* __restrict__ wm = role ? w2r : w2l;
    float acc[32];
    if (role) {
#pragma unroll
        for (int c = 0; c < 32; ++c) acc[c] = b2[c];
    } else {
#pragma unroll
        for (int c = 0; c < 32; ++c) acc[c] = 0.f;
    }
#pragma unroll
    for (int k = 0; k < 64; ++k) {
        float xk = xr[k];
#pragma unroll
        for (int c = 0; c < 32; ++c)
            acc[c] = fmaf(xk, wm[k * 32 + c], acc[c]);
    }
    if (!valid) return;
    if (role == 0) {
        alignas(16) __half2 hv[16];               // 32 halfs = 64 B = 4 float4
#pragma unroll
        for (int i = 0; i < 16; ++i)
            hv[i] = __floats2half2_rn(acc[2 * i], acc[2 * i + 1]);
        float4* op = (float4*)(zh + (size_t)node * 32);
#pragma unroll
        for (int i = 0; i < 4; ++i) op[i] = ((float4*)hv)[i];
    } else {
        float4* op = (float4*)(r + (size_t)node * 32);
#pragma unroll
        for (int i = 0; i < 8; ++i)
            op[i] = make_float4(acc[4 * i], acc[4 * i + 1], acc[4 * i + 2], acc[4 * i + 3]);
    }
}

// ---------------- agg2 + classifier: fully in-register, no LDS ----------------
__global__ __launch_bounds__(256) void k_agg2cls(const int* __restrict__ off,
                                                 const int* __restrict__ esrc,
                                                 const __half* __restrict__ zh,
                                                 const float* __restrict__ r,
                                                 const float* __restrict__ wc1,
                                                 const float* __restrict__ bc1,
                                                 const float* __restrict__ wc2,
                                                 const float* __restrict__ bc2,
                                                 float* __restrict__ out) {
    int wv = threadIdx.x >> 6, lane = threadIdx.x & 63;
    int node = blockIdx.x * 4 + wv;          // N % 4 == 0
    float w1c[32];
    float b1v = 0.f;
    if (lane < 16) {
#pragma unroll
        for (int k = 0; k < 32; ++k) w1c[k] = wc1[k * 16 + lane];
        b1v = bc1[lane];
    }
    float w2v[16];
    float b2v = 0.f;
    if (lane < 2) {
#pragma unroll
        for (int k = 0; k < 16; ++k) w2v[k] = wc2[k * 2 + lane];
        b2v = bc2[lane];
    }
    int s0 = off[node];
    int s1 = (node == N_NODES - 1) ? N_EDGES : off[node + 1];
    int eg = lane >> 2;                       // 0..15
    int cg = lane & 3;                        // halves cg*8 .. cg*8+7
    float a[8] = {0, 0, 0, 0, 0, 0, 0, 0};
    for (int i = s0; i < s1; i += 32) {
        int i0 = i + eg, i1 = i + 16 + eg;
        if (i0 < s1) {
            float4 rv = *(const float4*)(zh + (size_t)esrc[i0] * 32 + (cg << 3));
            const __half2* hp = (const __half2*)&rv;
            float2 f0 = __half22float2(hp[0]), f1 = __half22float2(hp[1]);
            float2 f2 = __half22float2(hp[2]), f3 = __half22float2(hp[3]);
            a[0] += f0.x; a[1] += f0.y; a[2] += f1.x; a[3] += f1.y;
            a[4] += f2.x; a[5] += f2.y; a[6] += f3.x; a[7] += f3.y;
        }
        if (i1 < s1) {
            float4 rv = *(const float4*)(zh + (size_t)esrc[i1] * 32 + (cg << 3));
            const __half2* hp = (const __half2*)&rv;
            float2 f0 = __half22float2(hp[0]), f1 = __half22float2(hp[1]);
            float2 f2 = __half22float2(hp[2]), f3 = __half22float2(hp[3]);
            a[0] += f0.x; a[1] += f0.y; a[2] += f1.x; a[3] += f1.y;
            a[4] += f2.x; a[5] += f2.y; a[6] += f3.x; a[7] += f3.y;
        }
    }
#pragma unroll
    for (int j = 0; j < 8; ++j) {
        a[j] += __shfl_xor(a[j], 4);
        a[j] += __shfl_xor(a[j], 8);
        a[j] += __shfl_xor(a[j], 16);
        a[j] += __shfl_xor(a[j], 32);
    }
    float inv = 1.0f / fmaxf((float)(s1 - s0), 1.0f);
    const float4* rp = (const float4*)(r + (size_t)node * 32 + (cg << 3));
    float4 r0 = rp[0], r1 = rp[1];
    float h2l[8];
    h2l[0] = fmaxf(fmaf(a[0], inv, r0.x), 0.f);
    h2l[1] = fmaxf(fmaf(a[1], inv, r0.y), 0.f);
    h2l[2] = fmaxf(fmaf(a[2], inv, r0.z), 0.f);
    h2l[3] = fmaxf(fmaf(a[3], inv, r0.w), 0.f);
    h2l[4] = fmaxf(fmaf(a[4], inv, r1.x), 0.f);
    h2l[5] = fmaxf(fmaf(a[5], inv, r1.y), 0.f);
    h2l[6] = fmaxf(fmaf(a[6], inv, r1.z), 0.f);
    h2l[7] = fmaxf(fmaf(a[7], inv, r1.w), 0.f);
    float h2f[32];
#pragma unroll
    for (int c = 0; c < 32; ++c) h2f[c] = __shfl(h2l[c & 7], c >> 3);
    float a1 = b1v;
#pragma unroll
    for (int k = 0; k < 32; ++k) a1 = fmaf(h2f[k], w1c[k], a1);
    a1 = fmaxf(a1, 0.f);
    float o = b2v;
#pragma unroll
    for (int k = 0; k < 16; ++k) {
        float h3k = __shfl(a1, k);
        o = fmaf(h3k, w2v[k], o);
    }
    float o1 = __shfl(o, 1);
    if (lane == 0) *(float2*)(out + (size_t)node * 2) = make_float2(o, o1);
}

extern "C" void kernel_launch(void* const* d_in, const int* in_sizes, int n_in,
                              void* d_out, int out_size, void* d_ws, size_t ws_size,
                              hipStream_t stream) {
    const float* x   = (const float*)d_in[0];
    const int*   ei  = (const int*)d_in[1];
    const int*   src = ei;
    const int*   dst = ei + N_EDGES;
    const float* w1l = (const float*)d_in[2];
    const float* w1r = (const float*)d_in[3];
    const float* b1  = (const float*)d_in[4];
    const float* w2l = (const float*)d_in[5];
    const float* w2r = (const float*)d_in[6];
    const float* b2  = (const float*)d_in[7];
    const float* wc1 = (const float*)d_in[8];
    const float* bc1 = (const float*)d_in[9];
    const float* wc2 = (const float*)d_in[10];
    const float* bc2 = (const float*)d_in[11];
    float* out = (float*)d_out;

    // ws layout (4B units):
    //   bincnt[400] | binoff[400] | bincur[400] | off[N] | binned[E] | esrc[E]
    //   | h1[64N] | q[64N] (reused: zh[16N]+r[32N]) | ph[32N]
    int*   wi     = (int*)d_ws;
    int*   bincnt = wi;
    int*   binoff = wi + 400;
    int*   bincur = wi + 800;
    int*   off    = wi + 1200;
    int*   binned = off + N_NODES;
    int*   esrc   = binned + N_EDGES;
    float* h1     = (float*)(esrc + N_EDGES);
    float* q      = h1 + (size_t)64 * N_NODES;
    float* phf    = q + (size_t)64 * N_NODES;
    __half* ph    = (__half*)phf;
    __half* zh    = (__half*)q;                       // overlay: q dead after agg1
    float*  r     = q + (size_t)16 * N_NODES;

    // ---- CSR build ----
    hipMemsetAsync(bincnt, 0, 400 * sizeof(int), stream);
    k_bhist<<<NBLK_E, 256, 0, stream>>>(dst, bincnt);
    k_bscan<<<1, 512, 0, stream>>>(bincnt, binoff, bincur);
    k_binA<<<NBLK_E, 256, 0, stream>>>(src, dst, bincur, binned);
    k_binB<<<NBINS, 256, 0, stream>>>(binoff, binned, off, esrc);

    // ---- layer 1 ----
    k_pre1<<<NGRP * 4, 256, 0, stream>>>(x, w1l, w1r, b1, ph, q);
    k_agg1<<<N_NODES / 4, 256, 0, stream>>>(off, esrc, ph, q, h1);

    // ---- layer 2 + classifier ----
    k_pre2<<<NGRP * 2, 256, 0, stream>>>(h1, w2l, w2r, b2, zh, r);
    k_agg2cls<<<N_NODES / 4, 256, 0, stream>>>(off, esrc, zh, r, wc1, bc1, wc2, bc2, out);
}

// Round 9
// 228.708 us; speedup vs baseline: 1.2476x; 1.0952x over previous
//
#include <hip/hip_runtime.h>
#include <hip/hip_fp16.h>

#define N_NODES 50000
#define N_EDGES 800000
#define NBINS   391          // ceil(50000/128), 128 dst nodes per bin
#define EPB     4096         // edges per block (bhist / binA)
#define NBLK_E  ((N_EDGES + EPB - 1) / EPB)
#define MAXSEG  4096         // pass-B LDS segment capacity (mean 2046)
#define NTILE   391          // ceil(50000/128) node tiles for pre kernels
#define LSTRIDE 129          // LDS [ch][node] stride: (ch*129+node)%32 conflict-free

// ---------------- bin-level histogram ----------------
__global__ void k_bhist(const int* __restrict__ dst, int* __restrict__ bincnt) {
    __shared__ int cnt[NBINS];
    int t = threadIdx.x;
    for (int i = t; i < NBINS; i += 256) cnt[i] = 0;
    __syncthreads();
    int base = blockIdx.x * EPB;
    int nE = min(EPB, N_EDGES - base);
    for (int i = t; i < nE; i += 256) atomicAdd(&cnt[dst[base + i] >> 7], 1);
    __syncthreads();
    for (int i = t; i < NBINS; i += 256) if (cnt[i]) atomicAdd(&bincnt[i], cnt[i]);
}

// ---------------- exclusive scan of bin counts ----------------
__global__ void k_bscan(const int* __restrict__ bincnt, int* __restrict__ binoff,
                        int* __restrict__ bincur) {
    __shared__ int tmp[512];
    int t = threadIdx.x;
    int v = (t < NBINS) ? bincnt[t] : 0;
    tmp[t] = v;
    __syncthreads();
    int val = v;
    for (int d = 1; d < 512; d <<= 1) {
        int add = (t >= d) ? tmp[t - d] : 0;
        __syncthreads();
        val += add;
        tmp[t] = val;
        __syncthreads();
    }
    if (t < NBINS) { binoff[t] = val - v; bincur[t] = val - v; }
    if (t == NBINS - 1) binoff[NBINS] = val;
}

// ---------------- pass A: LDS-staged bin scatter ----------------
__global__ void k_binA(const int* __restrict__ src, const int* __restrict__ dst,
                       int* __restrict__ bincur, int* __restrict__ binned) {
    __shared__ int cnt[NBINS];
    __shared__ int sc[512];
    __shared__ int lpos[NBINS];
    __shared__ int base[NBINS];
    __shared__ int stage[EPB];
    __shared__ unsigned short sbin[EPB];
    int t = threadIdx.x;
    int blkbase = blockIdx.x * EPB;
    int nE = min(EPB, N_EDGES - blkbase);
    for (int i = t; i < NBINS; i += 256) cnt[i] = 0;
    __syncthreads();
    int sv[16], dv[16];
#pragma unroll
    for (int k = 0; k < 16; ++k) {
        int e = blkbase + t + k * 256;
        if (e < N_EDGES) {
            sv[k] = src[e];
            dv[k] = dst[e];
            atomicAdd(&cnt[dv[k] >> 7], 1);
        } else dv[k] = -1;
    }
    __syncthreads();
    sc[t]       = (t < NBINS) ? cnt[t] : 0;
    sc[t + 256] = (t + 256 < NBINS) ? cnt[t + 256] : 0;
    __syncthreads();
    for (int d = 1; d < 512; d <<= 1) {
        int s0 = t, s1 = t + 256;
        int n0 = sc[s0] + ((s0 >= d) ? sc[s0 - d] : 0);
        int n1 = sc[s1] + ((s1 >= d) ? sc[s1 - d] : 0);
        __syncthreads();
        sc[s0] = n0; sc[s1] = n1;
        __syncthreads();
    }
    for (int b = t; b < NBINS; b += 256) {
        int excl = sc[b] - cnt[b];
        lpos[b] = excl;
        sc[b] = excl;
        if (cnt[b] > 0) base[b] = atomicAdd(&bincur[b], cnt[b]);
    }
    __syncthreads();
#pragma unroll
    for (int k = 0; k < 16; ++k) {
        if (dv[k] >= 0) {
            int b = dv[k] >> 7;
            int p = atomicAdd(&lpos[b], 1);
            stage[p] = (sv[k] & 0xFFFF) | ((dv[k] & 127) << 16);
            sbin[p] = (unsigned short)b;
        }
    }
    __syncthreads();
    for (int i = t; i < nE; i += 256) {
        int b = sbin[i];
        binned[base[b] + (i - sc[b])] = stage[i];
    }
}

// ---------------- pass B: per-bin counting sort; derives off[] ----------------
__global__ void k_binB(const int* __restrict__ binoff, const int* __restrict__ binned,
                       int* __restrict__ off, int* __restrict__ esrc) {
    __shared__ int cnt[128];
    __shared__ int tmp[128];
    __shared__ int cur[128];
    __shared__ int buf[MAXSEG];
    int b = blockIdx.x, t = threadIdx.x;
    int n0 = b << 7;
    int seg0 = binoff[b], seg1 = binoff[b + 1];
    int n = seg1 - seg0;
    if (t < 128) cnt[t] = 0;
    __syncthreads();
    for (int i = t; i < n; i += 256) atomicAdd(&cnt[binned[seg0 + i] >> 16], 1);
    __syncthreads();
    int v = (t < 128) ? cnt[t] : 0;
    if (t < 128) tmp[t] = v;
    __syncthreads();
    int val = v;
    for (int d = 1; d < 128; d <<= 1) {
        int add = (t >= d && t < 128) ? tmp[t - d] : 0;
        __syncthreads();
        if (t < 128) { val += add; tmp[t] = val; }
        __syncthreads();
    }
    if (t < 128) {
        int excl = val - v;
        cur[t] = excl;
        int node = n0 + t;
        if (node < N_NODES) off[node] = seg0 + excl;
    }
    __syncthreads();
    if (n <= MAXSEG) {
        for (int i = t; i < n; i += 256) {
            int w = binned[seg0 + i];
            int p = atomicAdd(&cur[w >> 16], 1);
            buf[p] = w & 0xFFFF;
        }
        __syncthreads();
        for (int i = t; i < n; i += 256) esrc[seg0 + i] = buf[i];
    } else {
        for (int i = t; i < n; i += 256) {
            int w = binned[seg0 + i];
            int p = atomicAdd(&cur[w >> 16], 1);
            esrc[seg0 + p] = w & 0xFFFF;
        }
    }
}

// ---------------- pre1: p = x@w1l (fp16), q = x@w1r + b1 (fp32) ----------------
// 512 thr = 4 roles x 128 nodes; x tile staged once in LDS transposed [ch][node]
// (stride 129, conflict-free); weights wave-uniform -> SGPR, pure VALU k-loop.
__global__ __launch_bounds__(512) void k_pre1(const float* __restrict__ x,
                                              const float* __restrict__ wl,
                                              const float* __restrict__ wr,
                                              const float* __restrict__ b,
                                              __half* __restrict__ ph,
                                              float* __restrict__ q) {
    __shared__ float sx[64 * LSTRIDE];
    int t = threadIdx.x;
    int g0 = blockIdx.x * 128;
#pragma unroll
    for (int i = 0; i < 4; ++i) {
        int f = t + i * 512;                  // 0..2047 float4 slots
        int nd = f >> 4, cq = f & 15;
        int gn = g0 + nd;
        float4 v = (gn < N_NODES) ? ((const float4*)x)[(size_t)gn * 16 + cq]
                                  : make_float4(0.f, 0.f, 0.f, 0.f);
        sx[(cq * 4 + 0) * LSTRIDE + nd] = v.x;
        sx[(cq * 4 + 1) * LSTRIDE + nd] = v.y;
        sx[(cq * 4 + 2) * LSTRIDE + nd] = v.z;
        sx[(cq * 4 + 3) * LSTRIDE + nd] = v.w;
    }
    __syncthreads();
    int role = __builtin_amdgcn_readfirstlane(t >> 7);   // 0..3, wave-uniform
    int wsel = role >> 1;
    int c0 = (role & 1) * 32;
    int ln = t & 127;
    int node = g0 + ln;
    const float* __restrict__ wm = wsel ? wr : wl;
    float acc[32];
    if (wsel) {
#pragma unroll
        for (int c = 0; c < 32; ++c) acc[c] = b[c0 + c];
    } else {
#pragma unroll
        for (int c = 0; c < 32; ++c) acc[c] = 0.f;
    }
#pragma unroll
    for (int k = 0; k < 64; ++k) {
        float xk = sx[k * LSTRIDE + ln];
#pragma unroll
        for (int c = 0; c < 32; ++c)
            acc[c] = fmaf(xk, wm[k * 64 + c0 + c], acc[c]);
    }
    if (node >= N_NODES) return;
    if (wsel == 0) {
        alignas(16) __half2 hv[16];
#pragma unroll
        for (int i = 0; i < 16; ++i)
            hv[i] = __floats2half2_rn(acc[2 * i], acc[2 * i + 1]);
        float4* op = (float4*)(ph + (size_t)node * 64 + c0);
#pragma unroll
        for (int i = 0; i < 4; ++i) op[i] = ((float4*)hv)[i];
    } else {
        float4* op = (float4*)(q + (size_t)node * 64 + c0);
#pragma unroll
        for (int i = 0; i < 8; ++i)
            op[i] = make_float4(acc[4 * i], acc[4 * i + 1], acc[4 * i + 2], acc[4 * i + 3]);
    }
}

// ---------------- agg1: h1 = relu(mean-gather(p) + q)  [pure gather, no LDS] ----------------
__global__ __launch_bounds__(256) void k_agg1(const int* __restrict__ off,
                                              const int* __restrict__ esrc,
                                              const __half* __restrict__ ph,
                                              const float* __restrict__ q,
                                              float* __restrict__ h1) {
    int wv = threadIdx.x >> 6, lane = threadIdx.x & 63;
    int node = blockIdx.x * 4 + wv;          // N % 4 == 0
    int s0 = off[node];
    int s1 = (node == N_NODES - 1) ? N_EDGES : off[node + 1];
    int eg = lane >> 3;                       // 0..7
    int cg = lane & 7;                        // halves cg*8 .. cg*8+7
    float a[8] = {0, 0, 0, 0, 0, 0, 0, 0};
    float c2[8] = {0, 0, 0, 0, 0, 0, 0, 0};
    for (int i = s0; i < s1; i += 16) {
        int i0 = i + eg, i1 = i + 8 + eg;
        if (i0 < s1) {
            float4 rv = *(const float4*)(ph + (size_t)esrc[i0] * 64 + (cg << 3));
            const __half2* hp = (const __half2*)&rv;
            float2 f0 = __half22float2(hp[0]), f1 = __half22float2(hp[1]);
            float2 f2 = __half22float2(hp[2]), f3 = __half22float2(hp[3]);
            a[0] += f0.x; a[1] += f0.y; a[2] += f1.x; a[3] += f1.y;
            a[4] += f2.x; a[5] += f2.y; a[6] += f3.x; a[7] += f3.y;
        }
        if (i1 < s1) {
            float4 rv = *(const float4*)(ph + (size_t)esrc[i1] * 64 + (cg << 3));
            const __half2* hp = (const __half2*)&rv;
            float2 f0 = __half22float2(hp[0]), f1 = __half22float2(hp[1]);
            float2 f2 = __half22float2(hp[2]), f3 = __half22float2(hp[3]);
            c2[0] += f0.x; c2[1] += f0.y; c2[2] += f1.x; c2[3] += f1.y;
            c2[4] += f2.x; c2[5] += f2.y; c2[6] += f3.x; c2[7] += f3.y;
        }
    }
#pragma unroll
    for (int j = 0; j < 8; ++j) a[j] += c2[j];
#pragma unroll
    for (int j = 0; j < 8; ++j) {
        a[j] += __shfl_xor(a[j], 8);
        a[j] += __shfl_xor(a[j], 16);
        a[j] += __shfl_xor(a[j], 32);
    }
    if (eg == 0) {
        float inv = 1.0f / fmaxf((float)(s1 - s0), 1.0f);
        const float4* qp = (const float4*)(q + (size_t)node * 64 + (cg << 3));
        float4 q0 = qp[0], q1 = qp[1];
        float4 o0, o1;
        o0.x = fmaxf(fmaf(a[0], inv, q0.x), 0.f);
        o0.y = fmaxf(fmaf(a[1], inv, q0.y), 0.f);
        o0.z = fmaxf(fmaf(a[2], inv, q0.z), 0.f);
        o0.w = fmaxf(fmaf(a[3], inv, q0.w), 0.f);
        o1.x = fmaxf(fmaf(a[4], inv, q1.x), 0.f);
        o1.y = fmaxf(fmaf(a[5], inv, q1.y), 0.f);
        o1.z = fmaxf(fmaf(a[6], inv, q1.z), 0.f);
        o1.w = fmaxf(fmaf(a[7], inv, q1.w), 0.f);
        float4* op = (float4*)(h1 + (size_t)node * 64 + (cg << 3));
        op[0] = o0; op[1] = o1;
    }
}

// ---------------- pre2: z = h1@w2l (fp16), r = h1@w2r + b2 (fp32) ----------------
// 256 thr = 2 roles x 128 nodes; same LDS-transposed stage + SGPR weights.
__global__ __launch_bounds__(256) void k_pre2(const float* __restrict__ h1,
                                              const float* __restrict__ w2l,
                                              const float* __restrict__ w2r,
                                              const float* __restrict__ b2,
                                              __half* __restrict__ zh,
                                              float* __restrict__ r) {
    __shared__ float sx[64 * LSTRIDE];
    int t = threadIdx.x;
    int g0 = blockIdx.x * 128;
#pragma unroll
    for (int i = 0; i < 8; ++i) {
        int f = t + i * 256;                  // 0..2047 float4 slots
        int nd = f >> 4, cq = f & 15;
        int gn = g0 + nd;
        float4 v = (gn < N_NODES) ? ((const float4*)h1)[(size_t)gn * 16 + cq]
                                  : make_float4(0.f, 0.f, 0.f, 0.f);
        sx[(cq * 4 + 0) * LSTRIDE + nd] = v.x;
        sx[(cq * 4 + 1) * LSTRIDE + nd] = v.y;
        sx[(cq * 4 + 2) * LSTRIDE + nd] = v.z;
        sx[(cq * 4 + 3) * LSTRIDE + nd] = v.w;
    }
    __syncthreads();
    int role = __builtin_amdgcn_readfirstlane(t >> 7);   // 0..1, wave-uniform
    int ln = t & 127;
    int node = g0 + ln;
    const float* __restrict__ wm = role ? w2r : w2l;
    float acc[32];
    if (role) {
#pragma unroll
        for (int c = 0; c < 32; ++c) acc[c] = b2[c];
    } else {
#pragma unroll
        for (int c = 0; c < 32; ++c) acc[c] = 0.f;
    }
#pragma unroll
    for (int k = 0; k < 64; ++k) {
        float xk = sx[k * LSTRIDE + ln];
#pragma unroll
        for (int c = 0; c < 32; ++c)
            acc[c] = fmaf(xk, wm[k * 32 + c], acc[c]);
    }
    if (node >= N_NODES) return;
    if (role == 0) {
        alignas(16) __half2 hv[16];
#pragma unroll
        for (int i = 0; i < 16; ++i)
            hv[i] = __floats2half2_rn(acc[2 * i], acc[2 * i + 1]);
        float4* op = (float4*)(zh + (size_t)node * 32);
#pragma unroll
        for (int i = 0; i < 4; ++i) op[i] = ((float4*)hv)[i];
    } else {
        float4* op = (float4*)(r + (size_t)node * 32);
#pragma unroll
        for (int i = 0; i < 8; ++i)
            op[i] = make_float4(acc[4 * i], acc[4 * i + 1], acc[4 * i + 2], acc[4 * i + 3]);
    }
}

// ---------------- agg2 + classifier: fully in-register, no LDS ----------------
__global__ __launch_bounds__(256) void k_agg2cls(const int* __restrict__ off,
                                                 const int* __restrict__ esrc,
                                                 const __half* __restrict__ zh,
                                                 const float* __restrict__ r,
                                                 const float* __restrict__ wc1,
                                                 const float* __restrict__ bc1,
                                                 const float* __restrict__ wc2,
                                                 const float* __restrict__ bc2,
                                                 float* __restrict__ out) {
    int wv = threadIdx.x >> 6, lane = threadIdx.x & 63;
    int node = blockIdx.x * 4 + wv;          // N % 4 == 0
    float w1c[32];
    float b1v = 0.f;
    if (lane < 16) {
#pragma unroll
        for (int k = 0; k < 32; ++k) w1c[k] = wc1[k * 16 + lane];
        b1v = bc1[lane];
    }
    float w2v[16];
    float b2v = 0.f;
    if (lane < 2) {
#pragma unroll
        for (int k = 0; k < 16; ++k) w2v[k] = wc2[k * 2 + lane];
        b2v = bc2[lane];
    }
    int s0 = off[node];
    int s1 = (node == N_NODES - 1) ? N_EDGES : off[node + 1];
    int eg = lane >> 2;                       // 0..15
    int cg = lane & 3;                        // halves cg*8 .. cg*8+7
    float a[8] = {0, 0, 0, 0, 0, 0, 0, 0};
    for (int i = s0; i < s1; i += 32) {
        int i0 = i + eg, i1 = i + 16 + eg;
        if (i0 < s1) {
            float4 rv = *(const float4*)(zh + (size_t)esrc[i0] * 32 + (cg << 3));
            const __half2* hp = (const __half2*)&rv;
            float2 f0 = __half22float2(hp[0]), f1 = __half22float2(hp[1]);
            float2 f2 = __half22float2(hp[2]), f3 = __half22float2(hp[3]);
            a[0] += f0.x; a[1] += f0.y; a[2] += f1.x; a[3] += f1.y;
            a[4] += f2.x; a[5] += f2.y; a[6] += f3.x; a[7] += f3.y;
        }
        if (i1 < s1) {
            float4 rv = *(const float4*)(zh + (size_t)esrc[i1] * 32 + (cg << 3));
            const __half2* hp = (const __half2*)&rv;
            float2 f0 = __half22float2(hp[0]), f1 = __half22float2(hp[1]);
            float2 f2 = __half22float2(hp[2]), f3 = __half22float2(hp[3]);
            a[0] += f0.x; a[1] += f0.y; a[2] += f1.x; a[3] += f1.y;
            a[4] += f2.x; a[5] += f2.y; a[6] += f3.x; a[7] += f3.y;
        }
    }
#pragma unroll
    for (int j = 0; j < 8; ++j) {
        a[j] += __shfl_xor(a[j], 4);
        a[j] += __shfl_xor(a[j], 8);
        a[j] += __shfl_xor(a[j], 16);
        a[j] += __shfl_xor(a[j], 32);
    }
    float inv = 1.0f / fmaxf((float)(s1 - s0), 1.0f);
    const float4* rp = (const float4*)(r + (size_t)node * 32 + (cg << 3));
    float4 r0 = rp[0], r1 = rp[1];
    float h2l[8];
    h2l[0] = fmaxf(fmaf(a[0], inv, r0.x), 0.f);
    h2l[1] = fmaxf(fmaf(a[1], inv, r0.y), 0.f);
    h2l[2] = fmaxf(fmaf(a[2], inv, r0.z), 0.f);
    h2l[3] = fmaxf(fmaf(a[3], inv, r0.w), 0.f);
    h2l[4] = fmaxf(fmaf(a[4], inv, r1.x), 0.f);
    h2l[5] = fmaxf(fmaf(a[5], inv, r1.y), 0.f);
    h2l[6] = fmaxf(fmaf(a[6], inv, r1.z), 0.f);
    h2l[7] = fmaxf(fmaf(a[7], inv, r1.w), 0.f);
    float h2f[32];
#pragma unroll
    for (int c = 0; c < 32; ++c) h2f[c] = __shfl(h2l[c & 7], c >> 3);
    float a1 = b1v;
#pragma unroll
    for (int k = 0; k < 32; ++k) a1 = fmaf(h2f[k], w1c[k], a1);
    a1 = fmaxf(a1, 0.f);
    float o = b2v;
#pragma unroll
    for (int k = 0; k < 16; ++k) {
        float h3k = __shfl(a1, k);
        o = fmaf(h3k, w2v[k], o);
    }
    float o1 = __shfl(o, 1);
    if (lane == 0) *(float2*)(out + (size_t)node * 2) = make_float2(o, o1);
}

extern "C" void kernel_launch(void* const* d_in, const int* in_sizes, int n_in,
                              void* d_out, int out_size, void* d_ws, size_t ws_size,
                              hipStream_t stream) {
    const float* x   = (const float*)d_in[0];
    const int*   ei  = (const int*)d_in[1];
    const int*   src = ei;
    const int*   dst = ei + N_EDGES;
    const float* w1l = (const float*)d_in[2];
    const float* w1r = (const float*)d_in[3];
    const float* b1  = (const float*)d_in[4];
    const float* w2l = (const float*)d_in[5];
    const float* w2r = (const float*)d_in[6];
    const float* b2  = (const float*)d_in[7];
    const float* wc1 = (const float*)d_in[8];
    const float* bc1 = (const float*)d_in[9];
    const float* wc2 = (const float*)d_in[10];
    const float* bc2 = (const float*)d_in[11];
    float* out = (float*)d_out;

    // ws layout (4B units):
    //   bincnt[400] | binoff[400] | bincur[400] | off[N] | binned[E] | esrc[E]
    //   | h1[64N] | q[64N] (reused: zh[16N]+r[32N]) | ph[32N]
    int*   wi     = (int*)d_ws;
    int*   bincnt = wi;
    int*   binoff = wi + 400;
    int*   bincur = wi + 800;
    int*   off    = wi + 1200;
    int*   binned = off + N_NODES;
    int*   esrc   = binned + N_EDGES;
    float* h1     = (float*)(esrc + N_EDGES);
    float* q      = h1 + (size_t)64 * N_NODES;
    float* phf    = q + (size_t)64 * N_NODES;
    __half* ph    = (__half*)phf;
    __half* zh    = (__half*)q;                       // overlay: q dead after agg1
    float*  r     = q + (size_t)16 * N_NODES;

    // ---- CSR build ----
    hipMemsetAsync(bincnt, 0, 400 * sizeof(int), stream);
    k_bhist<<<NBLK_E, 256, 0, stream>>>(dst, bincnt);
    k_bscan<<<1, 512, 0, stream>>>(bincnt, binoff, bincur);
    k_binA<<<NBLK_E, 256, 0, stream>>>(src, dst, bincur, binned);
    k_binB<<<NBINS, 256, 0, stream>>>(binoff, binned, off, esrc);

    // ---- layer 1 ----
    k_pre1<<<NTILE, 512, 0, stream>>>(x, w1l, w1r, b1, ph, q);
    k_agg1<<<N_NODES / 4, 256, 0, stream>>>(off, esrc, ph, q, h1);

    // ---- layer 2 + classifier ----
    k_pre2<<<NTILE, 256, 0, stream>>>(h1, w2l, w2r, b2, zh, r);
    k_agg2cls<<<N_NODES / 4, 256, 0, stream>>>(off, esrc, zh, r, wc1, bc1, wc2, bc2, out);
}

// Round 10
// 203.539 us; speedup vs baseline: 1.4018x; 1.1237x over previous
//
#include <hip/hip_runtime.h>
#include <hip/hip_fp16.h>

#define N_NODES 50000
#define N_EDGES 800000
#define NBINS   391          // ceil(50000/128), 128 dst nodes per bin
#define EPB     4096         // edges per block (bhist / binA)
#define NBLK_E  ((N_EDGES + EPB - 1) / EPB)
#define MAXSEG  4096         // pass-B LDS segment capacity (mean 2046)
#define NTILE   391          // ceil(50000/128) node tiles for pre kernels
#define LSTRIDE 129          // LDS [ch][node] stride, conflict-free
#define CSTRIDE 257          // k_cls LDS stride (256-node tile)

// ---------------- bin-level histogram ----------------
__global__ void k_bhist(const int* __restrict__ dst, int* __restrict__ bincnt) {
    __shared__ int cnt[NBINS];
    int t = threadIdx.x;
    for (int i = t; i < NBINS; i += 256) cnt[i] = 0;
    __syncthreads();
    int base = blockIdx.x * EPB;
    int nE = min(EPB, N_EDGES - base);
    for (int i = t; i < nE; i += 256) atomicAdd(&cnt[dst[base + i] >> 7], 1);
    __syncthreads();
    for (int i = t; i < NBINS; i += 256) if (cnt[i]) atomicAdd(&bincnt[i], cnt[i]);
}

// ---------------- exclusive scan of bin counts ----------------
__global__ void k_bscan(const int* __restrict__ bincnt, int* __restrict__ binoff,
                        int* __restrict__ bincur) {
    __shared__ int tmp[512];
    int t = threadIdx.x;
    int v = (t < NBINS) ? bincnt[t] : 0;
    tmp[t] = v;
    __syncthreads();
    int val = v;
    for (int d = 1; d < 512; d <<= 1) {
        int add = (t >= d) ? tmp[t - d] : 0;
        __syncthreads();
        val += add;
        tmp[t] = val;
        __syncthreads();
    }
    if (t < NBINS) { binoff[t] = val - v; bincur[t] = val - v; }
    if (t == NBINS - 1) binoff[NBINS] = val;
}

// ---------------- pass A: LDS-staged bin scatter ----------------
__global__ void k_binA(const int* __restrict__ src, const int* __restrict__ dst,
                       int* __restrict__ bincur, int* __restrict__ binned) {
    __shared__ int cnt[NBINS];
    __shared__ int sc[512];
    __shared__ int lpos[NBINS];
    __shared__ int base[NBINS];
    __shared__ int stage[EPB];
    __shared__ unsigned short sbin[EPB];
    int t = threadIdx.x;
    int blkbase = blockIdx.x * EPB;
    int nE = min(EPB, N_EDGES - blkbase);
    for (int i = t; i < NBINS; i += 256) cnt[i] = 0;
    __syncthreads();
    int sv[16], dv[16];
#pragma unroll
    for (int k = 0; k < 16; ++k) {
        int e = blkbase + t + k * 256;
        if (e < N_EDGES) {
            sv[k] = src[e];
            dv[k] = dst[e];
            atomicAdd(&cnt[dv[k] >> 7], 1);
        } else dv[k] = -1;
    }
    __syncthreads();
    sc[t]       = (t < NBINS) ? cnt[t] : 0;
    sc[t + 256] = (t + 256 < NBINS) ? cnt[t + 256] : 0;
    __syncthreads();
    for (int d = 1; d < 512; d <<= 1) {
        int s0 = t, s1 = t + 256;
        int n0 = sc[s0] + ((s0 >= d) ? sc[s0 - d] : 0);
        int n1 = sc[s1] + ((s1 >= d) ? sc[s1 - d] : 0);
        __syncthreads();
        sc[s0] = n0; sc[s1] = n1;
        __syncthreads();
    }
    for (int b = t; b < NBINS; b += 256) {
        int excl = sc[b] - cnt[b];
        lpos[b] = excl;
        sc[b] = excl;
        if (cnt[b] > 0) base[b] = atomicAdd(&bincur[b], cnt[b]);
    }
    __syncthreads();
#pragma unroll
    for (int k = 0; k < 16; ++k) {
        if (dv[k] >= 0) {
            int b = dv[k] >> 7;
            int p = atomicAdd(&lpos[b], 1);
            stage[p] = (sv[k] & 0xFFFF) | ((dv[k] & 127) << 16);
            sbin[p] = (unsigned short)b;
        }
    }
    __syncthreads();
    for (int i = t; i < nE; i += 256) {
        int b = sbin[i];
        binned[base[b] + (i - sc[b])] = stage[i];
    }
}

// ---------------- pass B: per-bin counting sort; derives off[] ----------------
__global__ void k_binB(const int* __restrict__ binoff, const int* __restrict__ binned,
                       int* __restrict__ off, int* __restrict__ esrc) {
    __shared__ int cnt[128];
    __shared__ int tmp[128];
    __shared__ int cur[128];
    __shared__ int buf[MAXSEG];
    int b = blockIdx.x, t = threadIdx.x;
    int n0 = b << 7;
    int seg0 = binoff[b], seg1 = binoff[b + 1];
    int n = seg1 - seg0;
    if (t < 128) cnt[t] = 0;
    __syncthreads();
    for (int i = t; i < n; i += 256) atomicAdd(&cnt[binned[seg0 + i] >> 16], 1);
    __syncthreads();
    int v = (t < 128) ? cnt[t] : 0;
    if (t < 128) tmp[t] = v;
    __syncthreads();
    int val = v;
    for (int d = 1; d < 128; d <<= 1) {
        int add = (t >= d && t < 128) ? tmp[t - d] : 0;
        __syncthreads();
        if (t < 128) { val += add; tmp[t] = val; }
        __syncthreads();
    }
    if (t < 128) {
        int excl = val - v;
        cur[t] = excl;
        int node = n0 + t;
        if (node < N_NODES) off[node] = seg0 + excl;
    }
    __syncthreads();
    if (n <= MAXSEG) {
        for (int i = t; i < n; i += 256) {
            int w = binned[seg0 + i];
            int p = atomicAdd(&cur[w >> 16], 1);
            buf[p] = w & 0xFFFF;
        }
        __syncthreads();
        for (int i = t; i < n; i += 256) esrc[seg0 + i] = buf[i];
    } else {
        for (int i = t; i < n; i += 256) {
            int w = binned[seg0 + i];
            int p = atomicAdd(&cur[w >> 16], 1);
            esrc[seg0 + p] = w & 0xFFFF;
        }
    }
}

// ---------------- pre1: p = x@w1l (fp16), q = x@w1r + b1 (fp32) ----------------
__global__ __launch_bounds__(512) void k_pre1(const float* __restrict__ x,
                                              const float* __restrict__ wl,
                                              const float* __restrict__ wr,
                                              const float* __restrict__ b,
                                              __half* __restrict__ ph,
                                              float* __restrict__ q) {
    __shared__ float sx[64 * LSTRIDE];
    int t = threadIdx.x;
    int g0 = blockIdx.x * 128;
#pragma unroll
    for (int i = 0; i < 4; ++i) {
        int f = t + i * 512;
        int nd = f >> 4, cq = f & 15;
        int gn = g0 + nd;
        float4 v = (gn < N_NODES) ? ((const float4*)x)[(size_t)gn * 16 + cq]
                                  : make_float4(0.f, 0.f, 0.f, 0.f);
        sx[(cq * 4 + 0) * LSTRIDE + nd] = v.x;
        sx[(cq * 4 + 1) * LSTRIDE + nd] = v.y;
        sx[(cq * 4 + 2) * LSTRIDE + nd] = v.z;
        sx[(cq * 4 + 3) * LSTRIDE + nd] = v.w;
    }
    __syncthreads();
    int role = __builtin_amdgcn_readfirstlane(t >> 7);
    int wsel = role >> 1;
    int c0 = (role & 1) * 32;
    int ln = t & 127;
    int node = g0 + ln;
    const float* __restrict__ wm = wsel ? wr : wl;
    float acc[32];
    if (wsel) {
#pragma unroll
        for (int c = 0; c < 32; ++c) acc[c] = b[c0 + c];
    } else {
#pragma unroll
        for (int c = 0; c < 32; ++c) acc[c] = 0.f;
    }
#pragma unroll
    for (int k = 0; k < 64; ++k) {
        float xk = sx[k * LSTRIDE + ln];
#pragma unroll
        for (int c = 0; c < 32; ++c)
            acc[c] = fmaf(xk, wm[k * 64 + c0 + c], acc[c]);
    }
    if (node >= N_NODES) return;
    if (wsel == 0) {
        alignas(16) __half2 hv[16];
#pragma unroll
        for (int i = 0; i < 16; ++i)
            hv[i] = __floats2half2_rn(acc[2 * i], acc[2 * i + 1]);
        float4* op = (float4*)(ph + (size_t)node * 64 + c0);
#pragma unroll
        for (int i = 0; i < 4; ++i) op[i] = ((float4*)hv)[i];
    } else {
        float4* op = (float4*)(q + (size_t)node * 64 + c0);
#pragma unroll
        for (int i = 0; i < 8; ++i)
            op[i] = make_float4(acc[4 * i], acc[4 * i + 1], acc[4 * i + 2], acc[4 * i + 3]);
    }
}

// dequant-accumulate 16B of halfs into 8 fp32 accs
__device__ __forceinline__ void acc8(float* a, float4 rv) {
    const __half2* hp = (const __half2*)&rv;
    float2 f0 = __half22float2(hp[0]), f1 = __half22float2(hp[1]);
    float2 f2 = __half22float2(hp[2]), f3 = __half22float2(hp[3]);
    a[0] += f0.x; a[1] += f0.y; a[2] += f1.x; a[3] += f1.y;
    a[4] += f2.x; a[5] += f2.y; a[6] += f3.x; a[7] += f3.y;
}

// ---------------- agg1: h1 = relu(mean-gather(p) + q) ----------------
// half-wave (32 lanes) per node: eg = 0..3 edge slots, cg = 0..7 16B groups.
__global__ __launch_bounds__(256) void k_agg1(const int* __restrict__ off,
                                              const int* __restrict__ esrc,
                                              const __half* __restrict__ ph,
                                              const float* __restrict__ q,
                                              float* __restrict__ h1) {
    int wv = threadIdx.x >> 6, lane = threadIdx.x & 63;
    int h = lane >> 5, l32 = lane & 31;
    int node = blockIdx.x * 8 + wv * 2 + h;  // N % 8 == 0
    int eg = l32 >> 3;                        // 0..3
    int cg = l32 & 7;                         // 16B group: halfs cg*8..cg*8+7
    int s0 = off[node];
    int s1 = (node == N_NODES - 1) ? N_EDGES : off[node + 1];
    float a[8] = {0, 0, 0, 0, 0, 0, 0, 0};
    float c2[8] = {0, 0, 0, 0, 0, 0, 0, 0};
    for (int i = s0; i < s1; i += 8) {
        int i0 = i + eg, i1 = i + 4 + eg;
        if (i0 < s1) acc8(a,  *(const float4*)(ph + (size_t)esrc[i0] * 64 + (cg << 3)));
        if (i1 < s1) acc8(c2, *(const float4*)(ph + (size_t)esrc[i1] * 64 + (cg << 3)));
    }
#pragma unroll
    for (int j = 0; j < 8; ++j) a[j] += c2[j];
#pragma unroll
    for (int j = 0; j < 8; ++j) {
        a[j] += __shfl_xor(a[j], 8);
        a[j] += __shfl_xor(a[j], 16);
    }
    if (eg == 0) {
        float inv = 1.0f / fmaxf((float)(s1 - s0), 1.0f);
        const float4* qp = (const float4*)(q + (size_t)node * 64 + (cg << 3));
        float4 q0 = qp[0], q1 = qp[1];
        float4 o0, o1;
        o0.x = fmaxf(fmaf(a[0], inv, q0.x), 0.f);
        o0.y = fmaxf(fmaf(a[1], inv, q0.y), 0.f);
        o0.z = fmaxf(fmaf(a[2], inv, q0.z), 0.f);
        o0.w = fmaxf(fmaf(a[3], inv, q0.w), 0.f);
        o1.x = fmaxf(fmaf(a[4], inv, q1.x), 0.f);
        o1.y = fmaxf(fmaf(a[5], inv, q1.y), 0.f);
        o1.z = fmaxf(fmaf(a[6], inv, q1.z), 0.f);
        o1.w = fmaxf(fmaf(a[7], inv, q1.w), 0.f);
        float4* op = (float4*)(h1 + (size_t)node * 64 + (cg << 3));
        op[0] = o0; op[1] = o1;
    }
}

// ---------------- pre2: z = h1@w2l (fp16), r = h1@w2r + b2 (fp32) ----------------
__global__ __launch_bounds__(256) void k_pre2(const float* __restrict__ h1,
                                              const float* __restrict__ w2l,
                                              const float* __restrict__ w2r,
                                              const float* __restrict__ b2,
                                              __half* __restrict__ zh,
                                              float* __restrict__ r) {
    __shared__ float sx[64 * LSTRIDE];
    int t = threadIdx.x;
    int g0 = blockIdx.x * 128;
#pragma unroll
    for (int i = 0; i < 8; ++i) {
        int f = t + i * 256;
        int nd = f >> 4, cq = f & 15;
        int gn = g0 + nd;
        float4 v = (gn < N_NODES) ? ((const float4*)h1)[(size_t)gn * 16 + cq]
                                  : make_float4(0.f, 0.f, 0.f, 0.f);
        sx[(cq * 4 + 0) * LSTRIDE + nd] = v.x;
        sx[(cq * 4 + 1) * LSTRIDE + nd] = v.y;
        sx[(cq * 4 + 2) * LSTRIDE + nd] = v.z;
        sx[(cq * 4 + 3) * LSTRIDE + nd] = v.w;
    }
    __syncthreads();
    int role = __builtin_amdgcn_readfirstlane(t >> 7);
    int ln = t & 127;
    int node = g0 + ln;
    const float* __restrict__ wm = role ? w2r : w2l;
    float acc[32];
    if (role) {
#pragma unroll
        for (int c = 0; c < 32; ++c) acc[c] = b2[c];
    } else {
#pragma unroll
        for (int c = 0; c < 32; ++c) acc[c] = 0.f;
    }
#pragma unroll
    for (int k = 0; k < 64; ++k) {
        float xk = sx[k * LSTRIDE + ln];
#pragma unroll
        for (int c = 0; c < 32; ++c)
            acc[c] = fmaf(xk, wm[k * 32 + c], acc[c]);
    }
    if (node >= N_NODES) return;
    if (role == 0) {
        alignas(16) __half2 hv[16];
#pragma unroll
        for (int i = 0; i < 16; ++i)
            hv[i] = __floats2half2_rn(acc[2 * i], acc[2 * i + 1]);
        float4* op = (float4*)(zh + (size_t)node * 32);
#pragma unroll
        for (int i = 0; i < 4; ++i) op[i] = ((float4*)hv)[i];
    } else {
        float4* op = (float4*)(r + (size_t)node * 32);
#pragma unroll
        for (int i = 0; i < 8; ++i)
            op[i] = make_float4(acc[4 * i], acc[4 * i + 1], acc[4 * i + 2], acc[4 * i + 3]);
    }
}

// ---------------- agg2: h2 = relu(mean-gather(z) + r) ----------------
// half-wave per node: eg = 0..7 edge slots, cg = 0..3 16B groups.
__global__ __launch_bounds__(256) void k_agg2(const int* __restrict__ off,
                                              const int* __restrict__ esrc,
                                              const __half* __restrict__ zh,
                                              const float* __restrict__ r,
                                              float* __restrict__ h2) {
    int wv = threadIdx.x >> 6, lane = threadIdx.x & 63;
    int h = lane >> 5, l32 = lane & 31;
    int node = blockIdx.x * 8 + wv * 2 + h;  // N % 8 == 0
    int eg = l32 >> 2;                        // 0..7
    int cg = l32 & 3;                         // 16B group: halfs cg*8..cg*8+7
    int s0 = off[node];
    int s1 = (node == N_NODES - 1) ? N_EDGES : off[node + 1];
    float a[8] = {0, 0, 0, 0, 0, 0, 0, 0};
    float c2[8] = {0, 0, 0, 0, 0, 0, 0, 0};
    for (int i = s0; i < s1; i += 16) {
        int i0 = i + eg, i1 = i + 8 + eg;
        if (i0 < s1) acc8(a,  *(const float4*)(zh + (size_t)esrc[i0] * 32 + (cg << 3)));
        if (i1 < s1) acc8(c2, *(const float4*)(zh + (size_t)esrc[i1] * 32 + (cg << 3)));
    }
#pragma unroll
    for (int j = 0; j < 8; ++j) a[j] += c2[j];
#pragma unroll
    for (int j = 0; j < 8; ++j) {
        a[j] += __shfl_xor(a[j], 4);
        a[j] += __shfl_xor(a[j], 8);
        a[j] += __shfl_xor(a[j], 16);
    }
    if (eg == 0) {
        float inv = 1.0f / fmaxf((float)(s1 - s0), 1.0f);
        const float4* rp = (const float4*)(r + (size_t)node * 32 + (cg << 3));
        float4 r0 = rp[0], r1 = rp[1];
        float4 o0, o1;
        o0.x = fmaxf(fmaf(a[0], inv, r0.x), 0.f);
        o0.y = fmaxf(fmaf(a[1], inv, r0.y), 0.f);
        o0.z = fmaxf(fmaf(a[2], inv, r0.z), 0.f);
        o0.w = fmaxf(fmaf(a[3], inv, r0.w), 0.f);
        o1.x = fmaxf(fmaf(a[4], inv, r1.x), 0.f);
        o1.y = fmaxf(fmaf(a[5], inv, r1.y), 0.f);
        o1.z = fmaxf(fmaf(a[6], inv, r1.z), 0.f);
        o1.w = fmaxf(fmaf(a[7], inv, r1.w), 0.f);
        float4* op = (float4*)(h2 + (size_t)node * 32 + (cg << 3));
        op[0] = o0; op[1] = o1;
    }
}

// ---------------- cls: out = relu(h2@wc1 + bc1)@wc2 + bc2 ----------------
// 1 node per thread; h2 tile LDS-transposed; weights wave-uniform (SGPR).
__global__ __launch_bounds__(256) void k_cls(const float* __restrict__ h2,
                                             const float* __restrict__ wc1,
                                             const float* __restrict__ bc1,
                                             const float* __restrict__ wc2,
                                             const float* __restrict__ bc2,
                                             float* __restrict__ out) {
    __shared__ float sh[32 * CSTRIDE];
    int t = threadIdx.x;
    int g0 = blockIdx.x * 256;
#pragma unroll
    for (int i = 0; i < 8; ++i) {
        int f = t + i * 256;                  // 0..2047 float4 slots
        int nd = f >> 3, cq = f & 7;
        int gn = g0 + nd;
        float4 v = (gn < N_NODES) ? ((const float4*)h2)[(size_t)gn * 8 + cq]
                                  : make_float4(0.f, 0.f, 0.f, 0.f);
        sh[(cq * 4 + 0) * CSTRIDE + nd] = v.x;
        sh[(cq * 4 + 1) * CSTRIDE + nd] = v.y;
        sh[(cq * 4 + 2) * CSTRIDE + nd] = v.z;
        sh[(cq * 4 + 3) * CSTRIDE + nd] = v.w;
    }
    __syncthreads();
    int node = g0 + t;
    float acc[16];
#pragma unroll
    for (int j = 0; j < 16; ++j) acc[j] = bc1[j];
#pragma unroll
    for (int k = 0; k < 32; ++k) {
        float xk = sh[k * CSTRIDE + t];
#pragma unroll
        for (int j = 0; j < 16; ++j)
            acc[j] = fmaf(xk, wc1[k * 16 + j], acc[j]);
    }
    float o0 = bc2[0], o1 = bc2[1];
#pragma unroll
    for (int j = 0; j < 16; ++j) {
        float aj = fmaxf(acc[j], 0.f);
        o0 = fmaf(aj, wc2[j * 2 + 0], o0);
        o1 = fmaf(aj, wc2[j * 2 + 1], o1);
    }
    if (node < N_NODES)
        *(float2*)(out + (size_t)node * 2) = make_float2(o0, o1);
}

extern "C" void kernel_launch(void* const* d_in, const int* in_sizes, int n_in,
                              void* d_out, int out_size, void* d_ws, size_t ws_size,
                              hipStream_t stream) {
    const float* x   = (const float*)d_in[0];
    const int*   ei  = (const int*)d_in[1];
    const int*   src = ei;
    const int*   dst = ei + N_EDGES;
    const float* w1l = (const float*)d_in[2];
    const float* w1r = (const float*)d_in[3];
    const float* b1  = (const float*)d_in[4];
    const float* w2l = (const float*)d_in[5];
    const float* w2r = (const float*)d_in[6];
    const float* b2  = (const float*)d_in[7];
    const float* wc1 = (const float*)d_in[8];
    const float* bc1 = (const float*)d_in[9];
    const float* wc2 = (const float*)d_in[10];
    const float* bc2 = (const float*)d_in[11];
    float* out = (float*)d_out;

    // ws layout (4B units):
    //   bincnt[400] | binoff[400] | bincur[400] | off[N] | binned[E] | esrc[E]
    //   | h1[64N] (first 32N reused as h2 after pre2) | q[64N] (zh[16N]+r[32N] overlay)
    //   | ph[32N halfs = 16N floats]
    int*   wi     = (int*)d_ws;
    int*   bincnt = wi;
    int*   binoff = wi + 400;
    int*   bincur = wi + 800;
    int*   off    = wi + 1200;
    int*   binned = off + N_NODES;
    int*   esrc   = binned + N_EDGES;
    float* h1     = (float*)(esrc + N_EDGES);
    float* q      = h1 + (size_t)64 * N_NODES;
    float* phf    = q + (size_t)64 * N_NODES;
    __half* ph    = (__half*)phf;
    __half* zh    = (__half*)q;                       // overlay: q dead after agg1
    float*  r     = q + (size_t)16 * N_NODES;
    float*  h2    = h1;                               // h1 dead after pre2

    // ---- CSR build ----
    hipMemsetAsync(bincnt, 0, 400 * sizeof(int), stream);
    k_bhist<<<NBLK_E, 256, 0, stream>>>(dst, bincnt);
    k_bscan<<<1, 512, 0, stream>>>(bincnt, binoff, bincur);
    k_binA<<<NBLK_E, 256, 0, stream>>>(src, dst, bincur, binned);
    k_binB<<<NBINS, 256, 0, stream>>>(binoff, binned, off, esrc);

    // ---- layer 1 ----
    k_pre1<<<NTILE, 512, 0, stream>>>(x, w1l, w1r, b1, ph, q);
    k_agg1<<<N_NODES / 8, 256, 0, stream>>>(off, esrc, ph, q, h1);

    // ---- layer 2 ----
    k_pre2<<<NTILE, 256, 0, stream>>>(h1, w2l, w2r, b2, zh, r);
    k_agg2<<<N_NODES / 8, 256, 0, stream>>>(off, esrc, zh, r, h2);

    // ---- classifier ----
    k_cls<<<(N_NODES + 255) / 256, 256, 0, stream>>>(h2, wc1, bc1, wc2, bc2, out);
}